// Round 1
// baseline (2750.290 us; speedup 1.0000x reference)
//
#include <hip/hip_runtime.h>
#include <hip/hip_bf16.h>

// Problem constants
#define B_   8
#define S_   1024
#define F_   768
#define E_   512
#define L_   4
#define H_   8
#define HD_  64
#define M_   (B_*S_)        // 8192 rows
#define SCALE_ 0.125f       // HD^-0.5
#define EPS_ 1e-5f

__device__ __forceinline__ int clamp_d(int x) {
    x = x < 0 ? 0 : x;
    return x > 4 ? 4 : x;
}

// ---------------------------------------------------------------------------
// GEMM: C[M,N] = A[M,K] @ W[K,N] + bias[N]
// 64x64 tile, BK=32, 256 threads, 4x4 per thread. fp32 VALU.
// ---------------------------------------------------------------------------
#define BM 64
#define BN 64
#define BK 32

__global__ __launch_bounds__(256, 4)
void gemm_bias(const float* __restrict__ A, const float* __restrict__ W,
               const float* __restrict__ bias, float* __restrict__ C,
               int M, int N, int K)
{
    __shared__ float As[BK][BM];   // [k][m] (transposed A tile)
    __shared__ float Bs[BK][BN];   // [k][n]

    const int tid = threadIdx.x;
    const int tx = tid & 15;       // n-dir, 4 cols each
    const int ty = tid >> 4;       // m-dir, 4 rows each
    const int bx = blockIdx.x;     // N tile index
    const int by = blockIdx.y;     // M tile index

    const float* Ab = A + (size_t)by * BM * K;
    const float* Wb = W + (size_t)bx * BN;

    float acc[4][4];
#pragma unroll
    for (int i = 0; i < 4; ++i)
#pragma unroll
        for (int j = 0; j < 4; ++j) acc[i][j] = 0.f;

    for (int k0 = 0; k0 < K; k0 += BK) {
        // A tile: 64x32 = 2048 floats = 512 float4, 2 per thread.
#pragma unroll
        for (int i = 0; i < 2; ++i) {
            int idx = tid + 256 * i;          // 0..511
            int r   = idx >> 3;               // 0..63
            int c4  = idx & 7;                // 0..7
            float4 a = *(const float4*)(Ab + (size_t)r * K + k0 + c4 * 4);
            As[c4*4+0][r] = a.x; As[c4*4+1][r] = a.y;
            As[c4*4+2][r] = a.z; As[c4*4+3][r] = a.w;
        }
        // B tile: 32x64 = 2048 floats, row-major, coalesced float4.
#pragma unroll
        for (int i = 0; i < 2; ++i) {
            int idx = tid + 256 * i;
            int r   = idx >> 4;               // 0..31 (k row)
            int c4  = idx & 15;               // 0..15
            *(float4*)&Bs[r][c4*4] = *(const float4*)(Wb + (size_t)(k0 + r) * N + c4 * 4);
        }
        __syncthreads();

#pragma unroll
        for (int kk = 0; kk < BK; ++kk) {
            float4 a = *(const float4*)&As[kk][ty*4];   // broadcast within tx-group
            float4 b = *(const float4*)&Bs[kk][tx*4];   // 2-way bank aliasing (free)
            const float av[4] = {a.x, a.y, a.z, a.w};
            const float bv[4] = {b.x, b.y, b.z, b.w};
#pragma unroll
            for (int i = 0; i < 4; ++i)
#pragma unroll
                for (int j = 0; j < 4; ++j)
                    acc[i][j] = fmaf(av[i], bv[j], acc[i][j]);
        }
        __syncthreads();
    }

    const int col = bx * BN + tx * 4;
    const float4 bb = *(const float4*)&bias[col];
#pragma unroll
    for (int i = 0; i < 4; ++i) {
        int r = by * BM + ty * 4 + i;
        float4 o;
        o.x = acc[i][0] + bb.x;
        o.y = acc[i][1] + bb.y;
        o.z = acc[i][2] + bb.z;
        o.w = acc[i][3] + bb.w;
        *(float4*)&C[(size_t)r * N + col] = o;
    }
}

// ---------------------------------------------------------------------------
// Fused attention for one layer, flash-style.
// Block = 256 threads handles one (b, head, 64-row q tile).
// scores = (q.k^T)*SCALE + dbias[l][clip(d,0,4)], online softmax, O = P.V
// q,k,v,out layouts: (B,S,H,HD) flattened = (M, E) with E-col = h*64+hd.
// ---------------------------------------------------------------------------
__global__ __launch_bounds__(256, 2)
void attn_fused(const float* __restrict__ q, const float* __restrict__ k,
                const float* __restrict__ v, const int* __restrict__ dist,
                const float* __restrict__ dbias, int layer,
                float* __restrict__ out)
{
    __shared__ float QsT[64][68];  // [hd][row], scaled by SCALE_
    __shared__ float KsT[64][68];  // [hd][col]
    __shared__ float Vs[64][68];   // [col][hd]
    __shared__ float Ps[64][68];   // [row][col]

    const int tid = threadIdx.x;
    const int tx = tid & 15;       // key-col dir (4 each)
    const int ty = tid >> 4;       // q-row dir (4 each)
    const int bid = blockIdx.x;
    const int qt = bid & 15;
    const int hh = (bid >> 4) & 7;
    const int b  = bid >> 7;
    const int q0 = qt * 64;

    float db[5];
#pragma unroll
    for (int i = 0; i < 5; ++i) db[i] = dbias[layer * 5 + i];

    // Load + transpose + pre-scale Q tile (64 rows x 64 hd)
#pragma unroll
    for (int i = 0; i < 4; ++i) {
        int idx = tid + 256 * i;           // 0..1023
        int r   = idx >> 4;                // 0..63
        int c4  = idx & 15;                // 0..15
        float4 a = *(const float4*)&q[(((size_t)(b * S_ + q0 + r)) * H_ + hh) * HD_ + c4 * 4];
        QsT[c4*4+0][r] = a.x * SCALE_; QsT[c4*4+1][r] = a.y * SCALE_;
        QsT[c4*4+2][r] = a.z * SCALE_; QsT[c4*4+3][r] = a.w * SCALE_;
    }

    float accO[4][4];
    float mr[4], lr[4];
#pragma unroll
    for (int i = 0; i < 4; ++i) {
        mr[i] = -1e30f; lr[i] = 0.f;
#pragma unroll
        for (int j = 0; j < 4; ++j) accO[i][j] = 0.f;
    }
    __syncthreads();

    for (int t0 = 0; t0 < S_; t0 += 64) {
        // Load K (transposed) and V (row-major) tiles
#pragma unroll
        for (int i = 0; i < 4; ++i) {
            int idx = tid + 256 * i;
            int r   = idx >> 4;
            int c4  = idx & 15;
            size_t base = (((size_t)(b * S_ + t0 + r)) * H_ + hh) * HD_ + c4 * 4;
            float4 a  = *(const float4*)&k[base];
            KsT[c4*4+0][r] = a.x; KsT[c4*4+1][r] = a.y;
            KsT[c4*4+2][r] = a.z; KsT[c4*4+3][r] = a.w;
            *(float4*)&Vs[r][c4*4] = *(const float4*)&v[base];
        }
        __syncthreads();

        // S_sub = Q . K^T  (each thread: 4 rows x 4 cols)
        float s[4][4];
#pragma unroll
        for (int i = 0; i < 4; ++i)
#pragma unroll
            for (int j = 0; j < 4; ++j) s[i][j] = 0.f;

#pragma unroll
        for (int kk = 0; kk < 64; ++kk) {
            float4 qa = *(const float4*)&QsT[kk][ty*4];
            float4 kb = *(const float4*)&KsT[kk][tx*4];
            const float av[4] = {qa.x, qa.y, qa.z, qa.w};
            const float bv[4] = {kb.x, kb.y, kb.z, kb.w};
#pragma unroll
            for (int i = 0; i < 4; ++i)
#pragma unroll
                for (int j = 0; j < 4; ++j)
                    s[i][j] = fmaf(av[i], bv[j], s[i][j]);
        }

        // distance bias
#pragma unroll
        for (int i = 0; i < 4; ++i) {
            const int4 dv = *(const int4*)&dist[((size_t)(b * S_ + q0 + ty*4 + i)) * S_ + t0 + tx*4];
            s[i][0] += db[clamp_d(dv.x)];
            s[i][1] += db[clamp_d(dv.y)];
            s[i][2] += db[clamp_d(dv.z)];
            s[i][3] += db[clamp_d(dv.w)];
        }

        // online softmax (reduce across the 16 tx-lanes sharing each row)
#pragma unroll
        for (int i = 0; i < 4; ++i) {
            float mt = fmaxf(fmaxf(s[i][0], s[i][1]), fmaxf(s[i][2], s[i][3]));
#pragma unroll
            for (int off = 1; off < 16; off <<= 1)
                mt = fmaxf(mt, __shfl_xor(mt, off, 64));
            float mn = fmaxf(mr[i], mt);
            float corr = __expf(mr[i] - mn);
            float p0 = __expf(s[i][0] - mn);
            float p1 = __expf(s[i][1] - mn);
            float p2 = __expf(s[i][2] - mn);
            float p3 = __expf(s[i][3] - mn);
            float rs = (p0 + p1) + (p2 + p3);
#pragma unroll
            for (int off = 1; off < 16; off <<= 1)
                rs += __shfl_xor(rs, off, 64);
            lr[i] = lr[i] * corr + rs;
            mr[i] = mn;
#pragma unroll
            for (int j = 0; j < 4; ++j) accO[i][j] *= corr;
            *(float4*)&Ps[ty*4+i][tx*4] = make_float4(p0, p1, p2, p3);
        }
        __syncthreads();

        // O += P . V   (thread: rows ty*4.., hd cols tx*4..)
#pragma unroll
        for (int c = 0; c < 64; ++c) {
            float4 vv = *(const float4*)&Vs[c][tx*4];
            float p0 = Ps[ty*4+0][c];
            float p1 = Ps[ty*4+1][c];
            float p2 = Ps[ty*4+2][c];
            float p3 = Ps[ty*4+3][c];
            accO[0][0] = fmaf(p0, vv.x, accO[0][0]);
            accO[0][1] = fmaf(p0, vv.y, accO[0][1]);
            accO[0][2] = fmaf(p0, vv.z, accO[0][2]);
            accO[0][3] = fmaf(p0, vv.w, accO[0][3]);
            accO[1][0] = fmaf(p1, vv.x, accO[1][0]);
            accO[1][1] = fmaf(p1, vv.y, accO[1][1]);
            accO[1][2] = fmaf(p1, vv.z, accO[1][2]);
            accO[1][3] = fmaf(p1, vv.w, accO[1][3]);
            accO[2][0] = fmaf(p2, vv.x, accO[2][0]);
            accO[2][1] = fmaf(p2, vv.y, accO[2][1]);
            accO[2][2] = fmaf(p2, vv.z, accO[2][2]);
            accO[2][3] = fmaf(p2, vv.w, accO[2][3]);
            accO[3][0] = fmaf(p3, vv.x, accO[3][0]);
            accO[3][1] = fmaf(p3, vv.y, accO[3][1]);
            accO[3][2] = fmaf(p3, vv.z, accO[3][2]);
            accO[3][3] = fmaf(p3, vv.w, accO[3][3]);
        }
        __syncthreads();
    }

    // epilogue: normalize and store (B,S,H,HD) layout
#pragma unroll
    for (int i = 0; i < 4; ++i) {
        float inv = 1.f / lr[i];
        float4 o = make_float4(accO[i][0]*inv, accO[i][1]*inv, accO[i][2]*inv, accO[i][3]*inv);
        *(float4*)&out[(((size_t)(b * S_ + q0 + ty*4 + i)) * H_ + hh) * HD_ + tx*4] = o;
    }
}

// ---------------------------------------------------------------------------
// Residual + LayerNorm: h = LN(h + o) * g + beta. One wave per row (E=512).
// ---------------------------------------------------------------------------
__global__ __launch_bounds__(256, 8)
void residual_ln(float* __restrict__ h, const float* __restrict__ o,
                 const float* __restrict__ g, const float* __restrict__ beta)
{
    const int wave = threadIdx.x >> 6;
    const int lane = threadIdx.x & 63;
    const int row  = blockIdx.x * 4 + wave;

    float* hr = h + (size_t)row * E_;
    const float* orow = o + (size_t)row * E_;

    float x[8];
    {
        float4 a  = *(const float4*)&hr[lane*4];
        float4 b4 = *(const float4*)&hr[256 + lane*4];
        float4 oa = *(const float4*)&orow[lane*4];
        float4 ob = *(const float4*)&orow[256 + lane*4];
        x[0] = a.x + oa.x; x[1] = a.y + oa.y; x[2] = a.z + oa.z; x[3] = a.w + oa.w;
        x[4] = b4.x + ob.x; x[5] = b4.y + ob.y; x[6] = b4.z + ob.z; x[7] = b4.w + ob.w;
    }
    float sum = 0.f, sq = 0.f;
#pragma unroll
    for (int i = 0; i < 8; ++i) { sum += x[i]; sq += x[i]*x[i]; }
#pragma unroll
    for (int off = 1; off < 64; off <<= 1) {
        sum += __shfl_xor(sum, off, 64);
        sq  += __shfl_xor(sq,  off, 64);
    }
    const float mean = sum * (1.f/512.f);
    const float var  = sq * (1.f/512.f) - mean*mean;
    const float inv  = rsqrtf(var + EPS_);

    float4 g0 = *(const float4*)&g[lane*4];
    float4 g1 = *(const float4*)&g[256 + lane*4];
    float4 be0 = *(const float4*)&beta[lane*4];
    float4 be1 = *(const float4*)&beta[256 + lane*4];

    float4 y0, y1;
    y0.x = (x[0]-mean)*inv*g0.x + be0.x;
    y0.y = (x[1]-mean)*inv*g0.y + be0.y;
    y0.z = (x[2]-mean)*inv*g0.z + be0.z;
    y0.w = (x[3]-mean)*inv*g0.w + be0.w;
    y1.x = (x[4]-mean)*inv*g1.x + be1.x;
    y1.y = (x[5]-mean)*inv*g1.y + be1.y;
    y1.z = (x[6]-mean)*inv*g1.z + be1.z;
    y1.w = (x[7]-mean)*inv*g1.w + be1.w;
    *(float4*)&hr[lane*4] = y0;
    *(float4*)&hr[256 + lane*4] = y1;
}

// ---------------------------------------------------------------------------
// Final head: t = h[b,0,:]; hid = relu(t@W1+b1) [512x256]; logits = hid@W2+b2.
// One block per batch element.
// ---------------------------------------------------------------------------
__global__ __launch_bounds__(256, 1)
void head_kernel(const float* __restrict__ h, const float* __restrict__ W1,
                 const float* __restrict__ b1, const float* __restrict__ W2,
                 const float* __restrict__ b2, float* __restrict__ out)
{
    __shared__ float tl[512];
    __shared__ float red[8];
    const int tid = threadIdx.x;
    const int b = blockIdx.x;

    const float* hr = h + (size_t)b * S_ * E_;   // row s=0
    *(float2*)&tl[tid*2] = *(const float2*)&hr[tid*2];
    __syncthreads();

    float acc = b1[tid];
    for (int kk = 0; kk < 512; ++kk)
        acc = fmaf(tl[kk], W1[kk * 256 + tid], acc);
    float hid = fmaxf(acc, 0.f);

    float p0 = hid * W2[tid*2 + 0];
    float p1 = hid * W2[tid*2 + 1];
#pragma unroll
    for (int off = 32; off; off >>= 1) {
        p0 += __shfl_down(p0, off, 64);
        p1 += __shfl_down(p1, off, 64);
    }
    if ((tid & 63) == 0) {
        red[(tid >> 6)*2 + 0] = p0;
        red[(tid >> 6)*2 + 1] = p1;
    }
    __syncthreads();
    if (tid == 0) {
        out[b*2 + 0] = red[0] + red[2] + red[4] + red[6] + b2[0];
        out[b*2 + 1] = red[1] + red[3] + red[5] + red[7] + b2[1];
    }
}

// ---------------------------------------------------------------------------
extern "C" void kernel_launch(void* const* d_in, const int* in_sizes, int n_in,
                              void* d_out, int out_size, void* d_ws, size_t ws_size,
                              hipStream_t stream)
{
    const float* x     = (const float*)d_in[0];
    const int*   dist  = (const int*)  d_in[1];
    const float* Win   = (const float*)d_in[2];
    const float* b_in  = (const float*)d_in[3];
    const float* Wq    = (const float*)d_in[4];
    const float* bq    = (const float*)d_in[5];
    const float* Wk    = (const float*)d_in[6];
    const float* bk    = (const float*)d_in[7];
    const float* Wv    = (const float*)d_in[8];
    const float* bv    = (const float*)d_in[9];
    const float* Wo    = (const float*)d_in[10];
    const float* bo    = (const float*)d_in[11];
    const float* dbias = (const float*)d_in[12];
    const float* ln_g  = (const float*)d_in[13];
    const float* ln_b  = (const float*)d_in[14];
    const float* W1    = (const float*)d_in[15];
    const float* b1    = (const float*)d_in[16];
    const float* W2    = (const float*)d_in[17];
    const float* b2    = (const float*)d_in[18];
    float* out = (float*)d_out;

    float* ws = (float*)d_ws;
    const size_t NME = (size_t)M_ * E_;          // 8192*512 floats = 16 MiB
    float* h  = ws;                              // persistent hidden state
    float* qb = ws + 1*NME;
    float* kb = ws + 2*NME;
    float* vb = ws + 3*NME;
    float* ob = ws + 4*NME;                      // attention output
    float* pb = qb;                              // o-projection reuses q buffer

    const dim3 blk(256);
    const dim3 ggrid(E_/BN, M_/BM);              // (8, 128)

    // h = x @ Win + b_in
    gemm_bias<<<ggrid, blk, 0, stream>>>(x, Win, b_in, h, M_, E_, F_);

    for (int l = 0; l < L_; ++l) {
        const size_t wo = (size_t)l * E_ * E_;
        gemm_bias<<<ggrid, blk, 0, stream>>>(h, Wq + wo, bq + l*E_, qb, M_, E_, E_);
        gemm_bias<<<ggrid, blk, 0, stream>>>(h, Wk + wo, bk + l*E_, kb, M_, E_, E_);
        gemm_bias<<<ggrid, blk, 0, stream>>>(h, Wv + wo, bv + l*E_, vb, M_, E_, E_);
        attn_fused<<<dim3(B_*H_*16), blk, 0, stream>>>(qb, kb, vb, dist, dbias, l, ob);
        gemm_bias<<<ggrid, blk, 0, stream>>>(ob, Wo + wo, bo + l*E_, pb, M_, E_, E_);
        residual_ln<<<dim3(M_/4), blk, 0, stream>>>(h, pb, ln_g + l*E_, ln_b + l*E_);
    }

    head_kernel<<<dim3(B_), blk, 0, stream>>>(h, W1, b1, W2, b2, out);
}

// Round 2
// 1199.189 us; speedup vs baseline: 2.2935x; 2.2935x over previous
//
#include <hip/hip_runtime.h>
#include <hip/hip_bf16.h>
#include <stdint.h>

// Problem constants
#define B_   8
#define S_   1024
#define F_   768
#define E_   512
#define L_   4
#define H_   8
#define HD_  64
#define M_   (B_*S_)        // 8192 rows
#define SCALE_ 0.125f       // HD^-0.5
#define EPS_ 1e-5f

typedef short bf8_t  __attribute__((ext_vector_type(8)));   // 8 bf16 = 4 VGPR (MFMA A/B frag)
typedef float f32x4  __attribute__((ext_vector_type(4)));   // MFMA C/D frag

static __device__ __forceinline__ uint16_t bfbits(float f) {
    __hip_bfloat16 h = __float2bfloat16(f);
    union { __hip_bfloat16 h; uint16_t u; } cv{h};
    return cv.u;
}
static __device__ __forceinline__ uint32_t pack2bf(float lo, float hi) {
    return (uint32_t)bfbits(lo) | ((uint32_t)bfbits(hi) << 16);
}

// ---------------------------------------------------------------------------
// Swizzled global->LDS staging (T2 both-sides pattern, m173/m201):
// LDS layout: [ROWS][8 slots of 16B] linear; slot holds data kc8 = slot ^ (row&7).
// global_load_lds writes lane*16 linearly, so the SOURCE address is pre-swizzled.
// Read side applies the same XOR -> 2-way bank aliasing only (free, m136).
// ---------------------------------------------------------------------------
template<int ROWS>
static __device__ __forceinline__ void stage_swz(const uint16_t* __restrict__ g, int ldK,
                                                 int k0, char* lds, int tid) {
    const int wave = tid >> 6, lane = tid & 63;
    constexpr int NI = ROWS / 8;          // total 1KB wave-instrs for this tile
    constexpr int PW = NI / 4;            // per wave (4 waves)
#pragma unroll
    for (int j = 0; j < PW; ++j) {
        const int I = wave * PW + j;                  // wave-uniform
        const int m = I * 8 + (lane >> 3);
        const int slot = lane & 7;
        const int kc8 = slot ^ (m & 7);
        const uint16_t* gp = g + (size_t)m * ldK + k0 + kc8 * 8;
        __builtin_amdgcn_global_load_lds((const __attribute__((address_space(1))) void*)gp,
                                         (__attribute__((address_space(3))) void*)(lds + I * 1024),
                                         16, 0, 0);
    }
}

// ---------------------------------------------------------------------------
// MFMA GEMM: C[M,N=512] = A[M,K] (bf16) @ W[K,N] (as Wt[N][K] bf16) + bias.
// 128x64 tile, BK=64, 256 threads (2x2 waves, each 64x32 = 4x2 16x16 frags).
// OUT_MODE: 0 = bf16 row-major, 1 = f32, 2 = f32 + bf16 mirror,
//           3 = bf16 transposed vT[b][col][s] (for attention V operand).
// ---------------------------------------------------------------------------
template<int OUT_MODE>
__global__ __launch_bounds__(256, 2)
void gemm_mfma(const uint16_t* __restrict__ A, const uint16_t* __restrict__ Wt,
               const float* __restrict__ bias, void* __restrict__ Cout,
               void* __restrict__ Cout2, int K)
{
    __shared__ __align__(16) char smA[128 * 128];   // 128 rows * 128B = 16KB
    __shared__ __align__(16) char smB[64 * 128];    // 8KB

    const int tid = threadIdx.x;
    const int lane = tid & 63;
    const int g = lane >> 4;
    const int l15 = lane & 15;
    const int wave = tid >> 6;
    const int wm = wave >> 1;            // m-offset 64*wm
    const int wn = wave & 1;             // n-offset 32*wn
    const int n0 = blockIdx.x * 64;
    const int m0 = blockIdx.y * 128;

    f32x4 acc[4][2];
#pragma unroll
    for (int i = 0; i < 4; ++i) {
        acc[i][0] = f32x4{0.f, 0.f, 0.f, 0.f};
        acc[i][1] = f32x4{0.f, 0.f, 0.f, 0.f};
    }

    for (int k0 = 0; k0 < K; k0 += 64) {
        stage_swz<128>(A  + (size_t)m0 * K, K, k0, smA, tid);
        stage_swz< 64>(Wt + (size_t)n0 * K, K, k0, smB, tid);
        __syncthreads();   // compiler drains vmcnt before s_barrier (m97 structure)

#pragma unroll
        for (int c = 0; c < 2; ++c) {
            bf8_t bfr[2];
#pragma unroll
            for (int nb = 0; nb < 2; ++nb) {
                const int n = wn * 32 + nb * 16 + l15;
                const int slot = (c * 4 + g) ^ (n & 7);
                bfr[nb] = *(const bf8_t*)(smB + n * 128 + slot * 16);
            }
#pragma unroll
            for (int mi = 0; mi < 4; ++mi) {
                const int m = wm * 64 + mi * 16 + l15;
                const int slot = (c * 4 + g) ^ (m & 7);
                bf8_t af = *(const bf8_t*)(smA + m * 128 + slot * 16);
#pragma unroll
                for (int nb = 0; nb < 2; ++nb)
                    acc[mi][nb] = __builtin_amdgcn_mfma_f32_16x16x32_bf16(af, bfr[nb], acc[mi][nb], 0, 0, 0);
            }
        }
        __syncthreads();
    }

    const int colbase = n0 + wn * 32;
    float bia[2] = { bias[colbase + l15], bias[colbase + 16 + l15] };

#pragma unroll
    for (int mi = 0; mi < 4; ++mi) {
#pragma unroll
        for (int nb = 0; nb < 2; ++nb) {
            const int col  = colbase + nb * 16 + l15;
            const int row0 = m0 + wm * 64 + mi * 16 + g * 4;   // C/D: row=(l>>4)*4+reg (m89)
            f32x4 v = acc[mi][nb];
            const float r0 = v.x + bia[nb], r1 = v.y + bia[nb];
            const float r2 = v.z + bia[nb], r3 = v.w + bia[nb];
            if (OUT_MODE == 0) {
                uint16_t* C = (uint16_t*)Cout;
                C[(size_t)(row0+0)*E_ + col] = bfbits(r0);
                C[(size_t)(row0+1)*E_ + col] = bfbits(r1);
                C[(size_t)(row0+2)*E_ + col] = bfbits(r2);
                C[(size_t)(row0+3)*E_ + col] = bfbits(r3);
            } else if (OUT_MODE == 1) {
                float* C = (float*)Cout;
                C[(size_t)(row0+0)*E_ + col] = r0;
                C[(size_t)(row0+1)*E_ + col] = r1;
                C[(size_t)(row0+2)*E_ + col] = r2;
                C[(size_t)(row0+3)*E_ + col] = r3;
            } else if (OUT_MODE == 2) {
                float* C = (float*)Cout;
                uint16_t* C2 = (uint16_t*)Cout2;
                C[(size_t)(row0+0)*E_ + col] = r0;
                C[(size_t)(row0+1)*E_ + col] = r1;
                C[(size_t)(row0+2)*E_ + col] = r2;
                C[(size_t)(row0+3)*E_ + col] = r3;
                C2[(size_t)(row0+0)*E_ + col] = bfbits(r0);
                C2[(size_t)(row0+1)*E_ + col] = bfbits(r1);
                C2[(size_t)(row0+2)*E_ + col] = bfbits(r2);
                C2[(size_t)(row0+3)*E_ + col] = bfbits(r3);
            } else {   // vT[b][col][s] bf16, rows r0..r3 are consecutive s
                uint16_t* C = (uint16_t*)Cout;
                const int b  = row0 >> 10;
                const int s0 = row0 & 1023;
                uint2 val{pack2bf(r0, r1), pack2bf(r2, r3)};
                *(uint2*)&C[((size_t)(b * E_ + col)) * S_ + s0] = val;
            }
        }
    }
}

// ---------------------------------------------------------------------------
// MFMA flash attention, swapped-QK^T (m214 pattern), LDS-free.
// Block = 256 thr = 4 waves; each wave: 16 q-rows x all 64 keys of each kv-tile.
// S^T = mfma(K, Q): lane holds q = l&15 (col), keys = f*16+(l>>4)*4+r (rows)
//  -> softmax per-q is lane-local + 2 shfl_xor.
// PV: out^T = mfma(V^T, P^T); V^T read straight from transposed global vT;
//  P^T redistributed to B-frag layout in-register (shfl + cndmask).
// ---------------------------------------------------------------------------
__global__ __launch_bounds__(256, 3)
void attn_mfma(const uint16_t* __restrict__ q, const uint16_t* __restrict__ k,
               const uint16_t* __restrict__ vT, const uint8_t* __restrict__ dT,
               const float* __restrict__ dbias, int layer, uint16_t* __restrict__ ob)
{
    const int tid = threadIdx.x, lane = tid & 63;
    const int g = lane >> 4, l15 = lane & 15, wq = tid >> 6;
    const int bid = blockIdx.x;
    const int qt = bid & 15, hh = (bid >> 4) & 7, b = bid >> 7;
    const int qrow = qt * 64 + wq * 16 + l15;        // this lane's q index

    const float db0 = dbias[layer*5+0], db1 = dbias[layer*5+1], db2 = dbias[layer*5+2],
                db3 = dbias[layer*5+3], db4 = dbias[layer*5+4];

    // Q frags (B operand: col=q=l&15, k=hd=(l>>4)*8+e per 32-k chunk)
    bf8_t qf[2];
    const uint16_t* qbase = q + ((size_t)(b * S_ + qrow)) * E_ + hh * 64;
#pragma unroll
    for (int c = 0; c < 2; ++c) qf[c] = *(const bf8_t*)(qbase + c * 32 + g * 8);

    f32x4 accO[4];
#pragma unroll
    for (int f = 0; f < 4; ++f) accO[f] = f32x4{0.f, 0.f, 0.f, 0.f};
    float mrun = -1e30f, lrun = 0.f;

    const uint16_t* kbase = k  + ((size_t)(b * S_)) * E_ + hh * 64;
    const uint16_t* vbase = vT + ((size_t)(b * E_ + hh * 64)) * S_;
    const uint8_t*  dbase = dT + ((size_t)(b * S_)) * S_ + qt * 64 + wq * 16 + l15;

    for (int t0 = 0; t0 < S_; t0 += 64) {
        // ---- S^T = K . Q^T ----
        f32x4 sc[4];
#pragma unroll
        for (int f = 0; f < 4; ++f) sc[f] = f32x4{0.f, 0.f, 0.f, 0.f};
#pragma unroll
        for (int f = 0; f < 4; ++f) {
#pragma unroll
            for (int c = 0; c < 2; ++c) {
                bf8_t kf = *(const bf8_t*)(kbase + (size_t)(t0 + f*16 + l15) * E_ + c*32 + g*8);
                sc[f] = __builtin_amdgcn_mfma_f32_16x16x32_bf16(kf, qf[c], sc[f], 0, 0, 0);
            }
        }
        // ---- distance bias + online softmax (natural-exp domain) ----
        float p[4][4];
        float tmax = -1e30f;
#pragma unroll
        for (int f = 0; f < 4; ++f) {
#pragma unroll
            for (int r = 0; r < 4; ++r) {
                const int d = dbase[(size_t)(t0 + f*16 + g*4 + r) * S_];
                const float bsel = d==0 ? db0 : d==1 ? db1 : d==2 ? db2 : d==3 ? db3 : db4;
                const float sv = fmaf(sc[f][r], SCALE_, bsel);
                p[f][r] = sv;
                tmax = fmaxf(tmax, sv);
            }
        }
        tmax = fmaxf(tmax, __shfl_xor(tmax, 16, 64));
        tmax = fmaxf(tmax, __shfl_xor(tmax, 32, 64));
        const float mnew = fmaxf(mrun, tmax);
        const float corr = __expf(mrun - mnew);
        float psum = 0.f;
#pragma unroll
        for (int f = 0; f < 4; ++f)
#pragma unroll
            for (int r = 0; r < 4; ++r) {
                p[f][r] = __expf(p[f][r] - mnew);
                psum += p[f][r];
            }
        psum += __shfl_xor(psum, 16, 64);
        psum += __shfl_xor(psum, 32, 64);
        lrun = fmaf(lrun, corr, psum);
        mrun = mnew;
#pragma unroll
        for (int f = 0; f < 4; ++f) accO[f] *= corr;

        // ---- pack P to bf16 pairs; redistribute S^T-layout -> B-frag layout ----
        uint32_t pk[4][2];
#pragma unroll
        for (int f = 0; f < 4; ++f) {
            pk[f][0] = pack2bf(p[f][0], p[f][1]);
            pk[f][1] = pack2bf(p[f][2], p[f][3]);
        }
        bf8_t pB[2];
#pragma unroll
        for (int c = 0; c < 2; ++c) {
            union { uint32_t w[4]; bf8_t v; } u;
#pragma unroll
            for (int j = 0; j < 4; ++j) {
                const int src = (((2*g + (j >> 1)) & 3) * 16) + l15;
                const uint32_t a  = (uint32_t)__shfl((int)pk[c*2+0][j & 1], src, 64);
                const uint32_t bb = (uint32_t)__shfl((int)pk[c*2+1][j & 1], src, 64);
                u.w[j] = (g >= 2) ? bb : a;
            }
            pB[c] = u.v;
        }
        // ---- O^T += V^T . P^T ----
#pragma unroll
        for (int c = 0; c < 2; ++c) {
#pragma unroll
            for (int f = 0; f < 4; ++f) {
                bf8_t vf = *(const bf8_t*)(vbase + (size_t)(f*16 + l15) * S_ + t0 + c*32 + g*8);
                accO[f] = __builtin_amdgcn_mfma_f32_16x16x32_bf16(vf, pB[c], accO[f], 0, 0, 0);
            }
        }
    }

    // epilogue: normalize, write ob[b*S+q][hh*64+hd] bf16 (hd = f*16+g*4+r)
    const float inv = 1.f / lrun;
    uint16_t* obase = ob + ((size_t)(b * S_ + qrow)) * E_ + hh * 64;
#pragma unroll
    for (int f = 0; f < 4; ++f) {
        f32x4 v = accO[f];
        uint2 val{pack2bf(v.x * inv, v.y * inv), pack2bf(v.z * inv, v.w * inv)};
        *(uint2*)(obase + f * 16 + g * 4) = val;
    }
}

// ---------------------------------------------------------------------------
// distances: clip to [0,4] and transpose to dT[b][key][q] u8 (bias gather
// becomes q-minor = coalesced for the swapped-QK^T lane layout).
// ---------------------------------------------------------------------------
__global__ __launch_bounds__(256, 4)
void dist_transpose(const int* __restrict__ dist, uint8_t* __restrict__ dT)
{
    __shared__ uint8_t sT[64][64];
    const int tid = threadIdx.x;
    const int q0 = blockIdx.x * 64, t0 = blockIdx.y * 64, b = blockIdx.z;
    const int r = tid >> 4, c4 = tid & 15;
#pragma unroll
    for (int i = 0; i < 4; ++i) {
        const int qq = r + i * 16;
        int4 d4 = *(const int4*)&dist[((size_t)(b * S_ + q0 + qq)) * S_ + t0 + c4 * 4];
        sT[c4*4+0][qq] = (uint8_t)min(max(d4.x, 0), 4);
        sT[c4*4+1][qq] = (uint8_t)min(max(d4.y, 0), 4);
        sT[c4*4+2][qq] = (uint8_t)min(max(d4.z, 0), 4);
        sT[c4*4+3][qq] = (uint8_t)min(max(d4.w, 0), 4);
    }
    __syncthreads();
    const int kk = tid >> 2, qc = tid & 3;
    int4 v = *(const int4*)&sT[kk][qc * 16];
    *(int4*)&dT[((size_t)(b * S_ + t0 + kk)) * S_ + q0 + qc * 16] = v;
}

// ---------------------------------------------------------------------------
// x (f32) -> bf16, vectorized 8/thread
// ---------------------------------------------------------------------------
__global__ void convert_bf16(const float* __restrict__ src, uint16_t* __restrict__ dst, int n8)
{
    const int i = blockIdx.x * 256 + threadIdx.x;
    if (i >= n8) return;
    float4 a = *(const float4*)&src[(size_t)i * 8];
    float4 b = *(const float4*)&src[(size_t)i * 8 + 4];
    uint4 o{pack2bf(a.x, a.y), pack2bf(a.z, a.w), pack2bf(b.x, b.y), pack2bf(b.z, b.w)};
    *(uint4*)&dst[(size_t)i * 8] = o;
}

// ---------------------------------------------------------------------------
// Weight transpose+convert: W[K][512] f32 -> Wt[512][K] bf16.
// blockIdx.z: 0=Win, 1..4=Wq[l], 5..8=Wk[l], 9..12=Wv[l], 13..16=Wo[l].
// ---------------------------------------------------------------------------
__global__ __launch_bounds__(256, 2)
void wtrans(const float* __restrict__ Win, const float* __restrict__ Wq,
            const float* __restrict__ Wk, const float* __restrict__ Wv,
            const float* __restrict__ Wo, uint16_t* __restrict__ Wt)
{
    __shared__ float ls[64][65];
    const int idx = blockIdx.z;
    const int Ki = (idx == 0) ? F_ : E_;
    if (blockIdx.x * 64 >= Ki) return;
    const float* src;
    size_t dstoff;
    if (idx == 0)       { src = Win;                              dstoff = 0; }
    else if (idx <= 4)  { src = Wq + (size_t)(idx-1)  * E_ * E_;  dstoff = (size_t)F_*E_ + (size_t)(idx-1)  * E_ * E_; }
    else if (idx <= 8)  { src = Wk + (size_t)(idx-5)  * E_ * E_;  dstoff = (size_t)F_*E_ + (size_t)(idx-1)  * E_ * E_; }
    else if (idx <= 12) { src = Wv + (size_t)(idx-9)  * E_ * E_;  dstoff = (size_t)F_*E_ + (size_t)(idx-1)  * E_ * E_; }
    else                { src = Wo + (size_t)(idx-13) * E_ * E_;  dstoff = (size_t)F_*E_ + (size_t)(idx-1)  * E_ * E_; }
    uint16_t* dst = Wt + dstoff;
    const int k0 = blockIdx.x * 64, n0 = blockIdx.y * 64;
    const int tid = threadIdx.x;
    const int r = tid >> 4, c4 = tid & 15;
#pragma unroll
    for (int i = 0; i < 4; ++i)
        *(float4*)&ls[r + i*16][c4*4] = *(const float4*)&src[(size_t)(k0 + r + i*16) * E_ + n0 + c4*4];
    __syncthreads();
#pragma unroll
    for (int i = 0; i < 2; ++i) {
        const int chunk = tid + 256 * i;        // 0..511
        const int n = chunk >> 3, kc = chunk & 7;
        uint4 o{pack2bf(ls[kc*8+0][n], ls[kc*8+1][n]),
                pack2bf(ls[kc*8+2][n], ls[kc*8+3][n]),
                pack2bf(ls[kc*8+4][n], ls[kc*8+5][n]),
                pack2bf(ls[kc*8+6][n], ls[kc*8+7][n])};
        *(uint4*)&dst[((size_t)(n0 + n)) * Ki + k0 + kc * 8] = o;
    }
}

// ---------------------------------------------------------------------------
// Residual + LayerNorm (fp32) + bf16 mirror write. One wave per row.
// ---------------------------------------------------------------------------
__global__ __launch_bounds__(256, 8)
void residual_ln(float* __restrict__ h, const float* __restrict__ o,
                 const float* __restrict__ g, const float* __restrict__ beta,
                 uint16_t* __restrict__ hb)
{
    const int wave = threadIdx.x >> 6;
    const int lane = threadIdx.x & 63;
    const int row  = blockIdx.x * 4 + wave;

    float* hr = h + (size_t)row * E_;
    const float* orow = o + (size_t)row * E_;

    float x[8];
    {
        float4 a  = *(const float4*)&hr[lane*4];
        float4 b4 = *(const float4*)&hr[256 + lane*4];
        float4 oa = *(const float4*)&orow[lane*4];
        float4 obv = *(const float4*)&orow[256 + lane*4];
        x[0] = a.x + oa.x; x[1] = a.y + oa.y; x[2] = a.z + oa.z; x[3] = a.w + oa.w;
        x[4] = b4.x + obv.x; x[5] = b4.y + obv.y; x[6] = b4.z + obv.z; x[7] = b4.w + obv.w;
    }
    float sum = 0.f, sq = 0.f;
#pragma unroll
    for (int i = 0; i < 8; ++i) { sum += x[i]; sq += x[i]*x[i]; }
#pragma unroll
    for (int off = 1; off < 64; off <<= 1) {
        sum += __shfl_xor(sum, off, 64);
        sq  += __shfl_xor(sq,  off, 64);
    }
    const float mean = sum * (1.f/512.f);
    const float var  = sq * (1.f/512.f) - mean*mean;
    const float inv  = rsqrtf(var + EPS_);

    float4 g0 = *(const float4*)&g[lane*4];
    float4 g1 = *(const float4*)&g[256 + lane*4];
    float4 be0 = *(const float4*)&beta[lane*4];
    float4 be1 = *(const float4*)&beta[256 + lane*4];

    float4 y0, y1;
    y0.x = (x[0]-mean)*inv*g0.x + be0.x;
    y0.y = (x[1]-mean)*inv*g0.y + be0.y;
    y0.z = (x[2]-mean)*inv*g0.z + be0.z;
    y0.w = (x[3]-mean)*inv*g0.w + be0.w;
    y1.x = (x[4]-mean)*inv*g1.x + be1.x;
    y1.y = (x[5]-mean)*inv*g1.y + be1.y;
    y1.z = (x[6]-mean)*inv*g1.z + be1.z;
    y1.w = (x[7]-mean)*inv*g1.w + be1.w;
    *(float4*)&hr[lane*4] = y0;
    *(float4*)&hr[256 + lane*4] = y1;

    uint16_t* hrow = hb + (size_t)row * E_;
    uint2 p0{pack2bf(y0.x, y0.y), pack2bf(y0.z, y0.w)};
    uint2 p1{pack2bf(y1.x, y1.y), pack2bf(y1.z, y1.w)};
    *(uint2*)&hrow[lane*4]       = p0;
    *(uint2*)&hrow[256 + lane*4] = p1;
}

// ---------------------------------------------------------------------------
// Final head (fp32, tiny): t = h[b,0,:]; relu(t@W1+b1)@W2+b2.
// ---------------------------------------------------------------------------
__global__ __launch_bounds__(256, 1)
void head_kernel(const float* __restrict__ h, const float* __restrict__ W1,
                 const float* __restrict__ b1, const float* __restrict__ W2,
                 const float* __restrict__ b2, float* __restrict__ out)
{
    __shared__ float tl[512];
    __shared__ float red[8];
    const int tid = threadIdx.x;
    const int b = blockIdx.x;

    const float* hr = h + (size_t)b * S_ * E_;
    *(float2*)&tl[tid*2] = *(const float2*)&hr[tid*2];
    __syncthreads();

    float acc = b1[tid];
    for (int kk = 0; kk < 512; ++kk)
        acc = fmaf(tl[kk], W1[kk * 256 + tid], acc);
    float hid = fmaxf(acc, 0.f);

    float p0 = hid * W2[tid*2 + 0];
    float p1 = hid * W2[tid*2 + 1];
#pragma unroll
    for (int off = 32; off; off >>= 1) {
        p0 += __shfl_down(p0, off, 64);
        p1 += __shfl_down(p1, off, 64);
    }
    if ((tid & 63) == 0) {
        red[(tid >> 6)*2 + 0] = p0;
        red[(tid >> 6)*2 + 1] = p1;
    }
    __syncthreads();
    if (tid == 0) {
        out[b*2 + 0] = red[0] + red[2] + red[4] + red[6] + b2[0];
        out[b*2 + 1] = red[1] + red[3] + red[5] + red[7] + b2[1];
    }
}

// ---------------------------------------------------------------------------
extern "C" void kernel_launch(void* const* d_in, const int* in_sizes, int n_in,
                              void* d_out, int out_size, void* d_ws, size_t ws_size,
                              hipStream_t stream)
{
    const float* x     = (const float*)d_in[0];
    const int*   dist  = (const int*)  d_in[1];
    const float* Win   = (const float*)d_in[2];
    const float* b_in  = (const float*)d_in[3];
    const float* Wq    = (const float*)d_in[4];
    const float* bq    = (const float*)d_in[5];
    const float* Wk    = (const float*)d_in[6];
    const float* bk    = (const float*)d_in[7];
    const float* Wv    = (const float*)d_in[8];
    const float* bv    = (const float*)d_in[9];
    const float* Wo    = (const float*)d_in[10];
    const float* bo    = (const float*)d_in[11];
    const float* dbias = (const float*)d_in[12];
    const float* ln_g  = (const float*)d_in[13];
    const float* ln_b  = (const float*)d_in[14];
    const float* W1    = (const float*)d_in[15];
    const float* b1    = (const float*)d_in[16];
    const float* W2    = (const float*)d_in[17];
    const float* b2    = (const float*)d_in[18];
    float* out = (float*)d_out;

    char* w8 = (char*)d_ws;
    float*    h    = (float*)   (w8);                      // 16 MB fp32 residual stream
    float*    pb   = (float*)   (w8 + (size_t)(16<<20));   // 16 MB fp32 o-proj out
    uint16_t* hbf  = (uint16_t*)(w8 + (size_t)(32<<20));   // 8 MB bf16 mirror of h
    uint16_t* qb   = (uint16_t*)(w8 + (size_t)(40<<20));   // 8 MB
    uint16_t* kb   = (uint16_t*)(w8 + (size_t)(48<<20));   // 8 MB
    uint16_t* vTb  = (uint16_t*)(w8 + (size_t)(56<<20));   // 8 MB  vT[b][col][s]
    uint16_t* obuf = (uint16_t*)(w8 + (size_t)(64<<20));   // 8 MB
    uint16_t* xb   = (uint16_t*)(w8 + (size_t)(72<<20));   // 12 MB
    uint16_t* Wt   = (uint16_t*)(w8 + (size_t)(84<<20));   // 8.75 MB transposed bf16 weights
    uint8_t*  dT   = (uint8_t*) (w8 + (size_t)(93<<20));   // 8 MB clipped dist^T
    // total ~101 MB

    const dim3 blk(256);
    const dim3 ggrid(E_/64, M_/128);     // (8, 64) = 512 blocks

    convert_bf16<<<dim3(M_*F_/8/256), blk, 0, stream>>>(x, xb, M_*F_/8);
    wtrans<<<dim3(12, 8, 17), blk, 0, stream>>>(Win, Wq, Wk, Wv, Wo, Wt);
    dist_transpose<<<dim3(16, 16, 8), blk, 0, stream>>>(dist, dT);

    // h = x @ Win + b_in  (fp32 + bf16 mirror)
    gemm_mfma<2><<<ggrid, blk, 0, stream>>>(xb, Wt, b_in, h, hbf, F_);

    for (int l = 0; l < L_; ++l) {
        const uint16_t* Wtq = Wt + (size_t)F_*E_ + (size_t)( 0 + l)*E_*E_;
        const uint16_t* Wtk = Wt + (size_t)F_*E_ + (size_t)( 4 + l)*E_*E_;
        const uint16_t* Wtv = Wt + (size_t)F_*E_ + (size_t)( 8 + l)*E_*E_;
        const uint16_t* Wto = Wt + (size_t)F_*E_ + (size_t)(12 + l)*E_*E_;
        gemm_mfma<0><<<ggrid, blk, 0, stream>>>(hbf, Wtq, bq + l*E_, qb,  nullptr, E_);
        gemm_mfma<0><<<ggrid, blk, 0, stream>>>(hbf, Wtk, bk + l*E_, kb,  nullptr, E_);
        gemm_mfma<3><<<ggrid, blk, 0, stream>>>(hbf, Wtv, bv + l*E_, vTb, nullptr, E_);
        attn_mfma<<<dim3(B_*H_*16), blk, 0, stream>>>(qb, kb, vTb, dT, dbias, l, obuf);
        gemm_mfma<1><<<ggrid, blk, 0, stream>>>(obuf, Wto, bo + l*E_, pb, nullptr, E_);
        residual_ln<<<dim3(M_/4), blk, 0, stream>>>(h, pb, ln_g + l*E_, ln_b + l*E_, hbf);
    }

    head_kernel<<<dim3(B_), blk, 0, stream>>>(h, W1, b1, W2, b2, out);
}

// Round 3
// 615.713 us; speedup vs baseline: 4.4668x; 1.9476x over previous
//
#include <hip/hip_runtime.h>
#include <hip/hip_bf16.h>
#include <stdint.h>

// Problem constants
#define B_   8
#define S_   1024
#define F_   768
#define E_   512
#define L_   4
#define H_   8
#define HD_  64
#define M_   (B_*S_)        // 8192 rows
#define SCALE_ 0.125f       // HD^-0.5
#define EPS_ 1e-5f

typedef short bf8_t  __attribute__((ext_vector_type(8)));   // 8 bf16 = 4 VGPR (MFMA A/B frag)
typedef float f32x4  __attribute__((ext_vector_type(4)));   // MFMA C/D frag

static __device__ __forceinline__ uint16_t bfbits(float f) {
    __hip_bfloat16 h = __float2bfloat16(f);
    union { __hip_bfloat16 h; uint16_t u; } cv{h};
    return cv.u;
}
static __device__ __forceinline__ uint32_t pack2bf(float lo, float hi) {
    return (uint32_t)bfbits(lo) | ((uint32_t)bfbits(hi) << 16);
}

// ---------------------------------------------------------------------------
// Swizzled global->LDS staging (T2 both-sides pattern, m173/m201):
// LDS layout: [ROWS][8 slots of 16B] linear; slot holds data kc8 = slot ^ (row&7).
// global_load_lds writes lane*16 linearly, so the SOURCE address is pre-swizzled.
// Read applies the same XOR -> even 8-lane spread per 16B slot column (full BW).
// ---------------------------------------------------------------------------
template<int ROWS>
static __device__ __forceinline__ void stage_swz(const uint16_t* __restrict__ g, int ldK,
                                                 int k0, char* lds, int tid) {
    const int wave = tid >> 6, lane = tid & 63;
    constexpr int NI = ROWS / 8;          // 1KB wave-instrs for this tile
    constexpr int PW = NI / 4;            // per wave (4 waves)
#pragma unroll
    for (int j = 0; j < PW; ++j) {
        const int I = wave * PW + j;                  // wave-uniform
        const int m = I * 8 + (lane >> 3);
        const int slot = lane & 7;
        const int kc8 = slot ^ (m & 7);
        const uint16_t* gp = g + (size_t)m * ldK + k0 + kc8 * 8;
        __builtin_amdgcn_global_load_lds((const __attribute__((address_space(1))) void*)gp,
                                         (__attribute__((address_space(3))) void*)(lds + I * 1024),
                                         16, 0, 0);
    }
}

// ---------------------------------------------------------------------------
// MFMA GEMM: C[M,N=512] = A[M,K] (bf16) @ W[K,N] (as Wt[N][K] bf16) + bias.
// 128x64 tile, BK=64, 256 threads (2x2 waves, each 64x32 = 4x2 16x16 frags).
// OUT_MODE: 1 = f32, 2 = f32 + bf16 mirror.
// ---------------------------------------------------------------------------
template<int OUT_MODE>
__global__ __launch_bounds__(256, 2)
void gemm_mfma(const uint16_t* __restrict__ A, const uint16_t* __restrict__ Wt,
               const float* __restrict__ bias, void* __restrict__ Cout,
               void* __restrict__ Cout2, int K)
{
    __shared__ __align__(16) char smA[128 * 128];   // 16KB
    __shared__ __align__(16) char smB[64 * 128];    // 8KB

    const int tid = threadIdx.x;
    const int lane = tid & 63;
    const int g = lane >> 4;
    const int l15 = lane & 15;
    const int wave = tid >> 6;
    const int wm = wave >> 1;
    const int wn = wave & 1;
    const int n0 = blockIdx.x * 64;
    const int m0 = blockIdx.y * 128;

    f32x4 acc[4][2];
#pragma unroll
    for (int i = 0; i < 4; ++i) {
        acc[i][0] = f32x4{0.f, 0.f, 0.f, 0.f};
        acc[i][1] = f32x4{0.f, 0.f, 0.f, 0.f};
    }

    for (int k0 = 0; k0 < K; k0 += 64) {
        stage_swz<128>(A  + (size_t)m0 * K, K, k0, smA, tid);
        stage_swz< 64>(Wt + (size_t)n0 * K, K, k0, smB, tid);
        __syncthreads();

#pragma unroll
        for (int c = 0; c < 2; ++c) {
            bf8_t bfr[2];
#pragma unroll
            for (int nb = 0; nb < 2; ++nb) {
                const int n = wn * 32 + nb * 16 + l15;
                const int slot = (c * 4 + g) ^ (n & 7);
                bfr[nb] = *(const bf8_t*)(smB + n * 128 + slot * 16);
            }
#pragma unroll
            for (int mi = 0; mi < 4; ++mi) {
                const int m = wm * 64 + mi * 16 + l15;
                const int slot = (c * 4 + g) ^ (m & 7);
                bf8_t af = *(const bf8_t*)(smA + m * 128 + slot * 16);
#pragma unroll
                for (int nb = 0; nb < 2; ++nb)
                    acc[mi][nb] = __builtin_amdgcn_mfma_f32_16x16x32_bf16(af, bfr[nb], acc[mi][nb], 0, 0, 0);
            }
        }
        __syncthreads();
    }

    const int colbase = n0 + wn * 32;
    float bia[2] = { bias[colbase + l15], bias[colbase + 16 + l15] };

#pragma unroll
    for (int mi = 0; mi < 4; ++mi) {
#pragma unroll
        for (int nb = 0; nb < 2; ++nb) {
            const int col  = colbase + nb * 16 + l15;
            const int row0 = m0 + wm * 64 + mi * 16 + g * 4;   // C/D: row=(l>>4)*4+reg (m89)
            f32x4 v = acc[mi][nb];
            const float r0 = v.x + bia[nb], r1 = v.y + bia[nb];
            const float r2 = v.z + bia[nb], r3 = v.w + bia[nb];
            if (OUT_MODE == 1) {
                float* C = (float*)Cout;
                C[(size_t)(row0+0)*E_ + col] = r0;
                C[(size_t)(row0+1)*E_ + col] = r1;
                C[(size_t)(row0+2)*E_ + col] = r2;
                C[(size_t)(row0+3)*E_ + col] = r3;
            } else {
                float* C = (float*)Cout;
                uint16_t* C2 = (uint16_t*)Cout2;
                C[(size_t)(row0+0)*E_ + col] = r0;
                C[(size_t)(row0+1)*E_ + col] = r1;
                C[(size_t)(row0+2)*E_ + col] = r2;
                C[(size_t)(row0+3)*E_ + col] = r3;
                C2[(size_t)(row0+0)*E_ + col] = bfbits(r0);
                C2[(size_t)(row0+1)*E_ + col] = bfbits(r1);
                C2[(size_t)(row0+2)*E_ + col] = bfbits(r2);
                C2[(size_t)(row0+3)*E_ + col] = bfbits(r3);
            }
        }
    }
}

// ---------------------------------------------------------------------------
// Merged QKV GEMM: A[M,512] @ Wqkv^T[1536,512] -> q (bf16 rm), k (bf16 rm),
// v (bf16 transposed vT[b][col][s]). Sections of 512 cols; block covers 64
// cols so never straddles a section.
// ---------------------------------------------------------------------------
__global__ __launch_bounds__(256, 2)
void gemm_qkv(const uint16_t* __restrict__ A, const uint16_t* __restrict__ Wt,
              const float* __restrict__ bqp, const float* __restrict__ bkp,
              const float* __restrict__ bvp,
              uint16_t* __restrict__ qb, uint16_t* __restrict__ kb,
              uint16_t* __restrict__ vTb)
{
    __shared__ __align__(16) char smA[128 * 128];
    __shared__ __align__(16) char smB[64 * 128];

    const int tid = threadIdx.x;
    const int lane = tid & 63;
    const int g = lane >> 4;
    const int l15 = lane & 15;
    const int wave = tid >> 6;
    const int wm = wave >> 1;
    const int wn = wave & 1;
    const int n0 = blockIdx.x * 64;      // 0..1535
    const int m0 = blockIdx.y * 128;
    const int sec = n0 >> 9;             // 0=q 1=k 2=v

    f32x4 acc[4][2];
#pragma unroll
    for (int i = 0; i < 4; ++i) {
        acc[i][0] = f32x4{0.f, 0.f, 0.f, 0.f};
        acc[i][1] = f32x4{0.f, 0.f, 0.f, 0.f};
    }

    for (int k0 = 0; k0 < E_; k0 += 64) {
        stage_swz<128>(A  + (size_t)m0 * E_, E_, k0, smA, tid);
        stage_swz< 64>(Wt + (size_t)n0 * E_, E_, k0, smB, tid);
        __syncthreads();

#pragma unroll
        for (int c = 0; c < 2; ++c) {
            bf8_t bfr[2];
#pragma unroll
            for (int nb = 0; nb < 2; ++nb) {
                const int n = wn * 32 + nb * 16 + l15;
                const int slot = (c * 4 + g) ^ (n & 7);
                bfr[nb] = *(const bf8_t*)(smB + n * 128 + slot * 16);
            }
#pragma unroll
            for (int mi = 0; mi < 4; ++mi) {
                const int m = wm * 64 + mi * 16 + l15;
                const int slot = (c * 4 + g) ^ (m & 7);
                bf8_t af = *(const bf8_t*)(smA + m * 128 + slot * 16);
#pragma unroll
                for (int nb = 0; nb < 2; ++nb)
                    acc[mi][nb] = __builtin_amdgcn_mfma_f32_16x16x32_bf16(af, bfr[nb], acc[mi][nb], 0, 0, 0);
            }
        }
        __syncthreads();
    }

    const float* bp = sec == 0 ? bqp : sec == 1 ? bkp : bvp;
    const int colbase = n0 + wn * 32;
    const int cb511 = colbase & 511;
    float bia[2] = { bp[cb511 + l15], bp[cb511 + 16 + l15] };

#pragma unroll
    for (int mi = 0; mi < 4; ++mi) {
#pragma unroll
        for (int nb = 0; nb < 2; ++nb) {
            const int col  = cb511 + nb * 16 + l15;       // 0..511 within section
            const int row0 = m0 + wm * 64 + mi * 16 + g * 4;
            f32x4 v = acc[mi][nb];
            const float r0 = v.x + bia[nb], r1 = v.y + bia[nb];
            const float r2 = v.z + bia[nb], r3 = v.w + bia[nb];
            if (sec < 2) {
                uint16_t* C = sec == 0 ? qb : kb;
                C[(size_t)(row0+0)*E_ + col] = bfbits(r0);
                C[(size_t)(row0+1)*E_ + col] = bfbits(r1);
                C[(size_t)(row0+2)*E_ + col] = bfbits(r2);
                C[(size_t)(row0+3)*E_ + col] = bfbits(r3);
            } else {
                const int b  = row0 >> 10;
                const int s0 = row0 & 1023;
                uint2 val{pack2bf(r0, r1), pack2bf(r2, r3)};
                *(uint2*)&vTb[((size_t)(b * E_ + col)) * S_ + s0] = val;
            }
        }
    }
}

// ---------------------------------------------------------------------------
// MFMA flash attention v3: LDS double-buffered K/V tiles (m97 pipeline),
// register-prefetched distance bytes, swapped-QK^T softmax (lane-local).
// Block = 256 thr = 4 waves, one (b, head, 64-q tile); 16 kv-tiles of 64.
// ---------------------------------------------------------------------------
__global__ __launch_bounds__(256, 3)
void attn_mfma(const uint16_t* __restrict__ q, const uint16_t* __restrict__ k,
               const uint16_t* __restrict__ vT, const uint8_t* __restrict__ dT,
               const float* __restrict__ dbias, int layer, uint16_t* __restrict__ ob)
{
    __shared__ __align__(16) char Kb[2][64 * 128];   // 8KB per buf
    __shared__ __align__(16) char Vb[2][64 * 128];   // (V^T: rows=hd, cols=keys)

    const int tid = threadIdx.x, lane = tid & 63;
    const int g = lane >> 4, l15 = lane & 15, wq = tid >> 6;
    const int bid = blockIdx.x;
    const int qt = bid & 15, hh = (bid >> 4) & 7, b = bid >> 7;
    const int qrow = qt * 64 + wq * 16 + l15;

    const float db0 = dbias[layer*5+0], db1 = dbias[layer*5+1], db2 = dbias[layer*5+2],
                db3 = dbias[layer*5+3], db4 = dbias[layer*5+4];

    // Q frags (B operand: col=q=l&15, k=hd=(l>>4)*8+e per 32-k chunk)
    bf8_t qf[2];
    const uint16_t* qbase = q + ((size_t)(b * S_ + qrow)) * E_ + hh * 64;
#pragma unroll
    for (int c = 0; c < 2; ++c) qf[c] = *(const bf8_t*)(qbase + c * 32 + g * 8);

    f32x4 accO[4];
#pragma unroll
    for (int f = 0; f < 4; ++f) accO[f] = f32x4{0.f, 0.f, 0.f, 0.f};
    float mrun = -1e30f, lrun = 0.f;

    const uint16_t* kTile = k  + ((size_t)(b * S_)) * E_ + hh * 64;   // + key*E_
    const uint16_t* vTile = vT + ((size_t)(b * E_ + hh * 64)) * S_;   // + hd*S_ + key
    const uint8_t*  dbase = dT + ((size_t)(b * S_)) * S_ + qt * 64 + wq * 16 + l15;

    // ---- prologue: stage tile 0, prefetch d bytes for tile 0 ----
    stage_swz<64>(kTile, E_, 0, Kb[0], tid);
    stage_swz<64>(vTile, S_, 0, Vb[0], tid);
    int dcur[16];
#pragma unroll
    for (int f = 0; f < 4; ++f)
#pragma unroll
        for (int r = 0; r < 4; ++r)
            dcur[f*4+r] = dbase[(size_t)(f*16 + g*4 + r) * S_];
    __syncthreads();

    for (int t = 0; t < 16; ++t) {
        const int cur = t & 1;
        char* kc_ = Kb[cur];
        char* vc_ = Vb[cur];
        // issue next-tile staging (latency hidden under this tile's compute)
        if (t < 15) {
            stage_swz<64>(kTile + (size_t)(t + 1) * 64 * E_, E_, 0, Kb[cur ^ 1], tid);
            stage_swz<64>(vTile, S_, (t + 1) * 64, Vb[cur ^ 1], tid);
        }
        // next-tile d bytes into regs
        int dnxt[16];
#pragma unroll
        for (int f = 0; f < 4; ++f)
#pragma unroll
            for (int r = 0; r < 4; ++r)
                dnxt[f*4+r] = (t < 15) ? (int)dbase[(size_t)((t+1)*64 + f*16 + g*4 + r) * S_] : 0;

        // ---- S^T = K . Q^T ----
        f32x4 sc[4];
#pragma unroll
        for (int f = 0; f < 4; ++f) sc[f] = f32x4{0.f, 0.f, 0.f, 0.f};
        __builtin_amdgcn_s_setprio(1);
#pragma unroll
        for (int f = 0; f < 4; ++f) {
#pragma unroll
            for (int c = 0; c < 2; ++c) {
                const int slot = (c * 4 + g) ^ (l15 & 7);
                bf8_t kf = *(const bf8_t*)(kc_ + (f*16 + l15) * 128 + slot * 16);
                sc[f] = __builtin_amdgcn_mfma_f32_16x16x32_bf16(kf, qf[c], sc[f], 0, 0, 0);
            }
        }
        __builtin_amdgcn_s_setprio(0);

        // ---- distance bias + online softmax (lane-local rows) ----
        float p[4][4];
        float tmax = -1e30f;
#pragma unroll
        for (int f = 0; f < 4; ++f) {
#pragma unroll
            for (int r = 0; r < 4; ++r) {
                const int d = dcur[f*4+r];
                const float bsel = d==0 ? db0 : d==1 ? db1 : d==2 ? db2 : d==3 ? db3 : db4;
                const float sv = fmaf(sc[f][r], SCALE_, bsel);
                p[f][r] = sv;
                tmax = fmaxf(tmax, sv);
            }
        }
        tmax = fmaxf(tmax, __shfl_xor(tmax, 16, 64));
        tmax = fmaxf(tmax, __shfl_xor(tmax, 32, 64));
        const float mnew = fmaxf(mrun, tmax);
        const float corr = __expf(mrun - mnew);
        float psum = 0.f;
#pragma unroll
        for (int f = 0; f < 4; ++f)
#pragma unroll
            for (int r = 0; r < 4; ++r) {
                p[f][r] = __expf(p[f][r] - mnew);
                psum += p[f][r];
            }
        psum += __shfl_xor(psum, 16, 64);
        psum += __shfl_xor(psum, 32, 64);
        lrun = fmaf(lrun, corr, psum);
        mrun = mnew;
#pragma unroll
        for (int f = 0; f < 4; ++f) accO[f] *= corr;

        // ---- pack P; redistribute S^T-layout -> B-frag layout ----
        uint32_t pk[4][2];
#pragma unroll
        for (int f = 0; f < 4; ++f) {
            pk[f][0] = pack2bf(p[f][0], p[f][1]);
            pk[f][1] = pack2bf(p[f][2], p[f][3]);
        }
        bf8_t pB[2];
#pragma unroll
        for (int c = 0; c < 2; ++c) {
            union { uint32_t w[4]; bf8_t v; } u;
#pragma unroll
            for (int j = 0; j < 4; ++j) {
                const int src = (((2*g + (j >> 1)) & 3) * 16) + l15;
                const uint32_t a  = (uint32_t)__shfl((int)pk[c*2+0][j & 1], src, 64);
                const uint32_t bb = (uint32_t)__shfl((int)pk[c*2+1][j & 1], src, 64);
                u.w[j] = (g >= 2) ? bb : a;
            }
            pB[c] = u.v;
        }

        // ---- O^T += V^T . P^T ----
        __builtin_amdgcn_s_setprio(1);
#pragma unroll
        for (int c = 0; c < 2; ++c) {
#pragma unroll
            for (int f = 0; f < 4; ++f) {
                const int slot = (c * 4 + g) ^ (l15 & 7);
                bf8_t vf = *(const bf8_t*)(vc_ + (f*16 + l15) * 128 + slot * 16);
                accO[f] = __builtin_amdgcn_mfma_f32_16x16x32_bf16(vf, pB[c], accO[f], 0, 0, 0);
            }
        }
        __builtin_amdgcn_s_setprio(0);

        __syncthreads();   // staging of t+1 drained; all waves done with buf[cur]
#pragma unroll
        for (int i = 0; i < 16; ++i) dcur[i] = dnxt[i];
    }

    // epilogue: normalize, write ob[b*S+q][hh*64+hd] bf16 (hd = f*16+g*4+r)
    const float inv = 1.f / lrun;
    uint16_t* obase = ob + ((size_t)(b * S_ + qrow)) * E_ + hh * 64;
#pragma unroll
    for (int f = 0; f < 4; ++f) {
        f32x4 v = accO[f];
        uint2 val{pack2bf(v.x * inv, v.y * inv), pack2bf(v.z * inv, v.w * inv)};
        *(uint2*)(obase + f * 16 + g * 4) = val;
    }
}

// ---------------------------------------------------------------------------
// distances: clip to [0,4] and transpose to dT[b][key][q] u8.
// ---------------------------------------------------------------------------
__global__ __launch_bounds__(256, 4)
void dist_transpose(const int* __restrict__ dist, uint8_t* __restrict__ dT)
{
    __shared__ uint8_t sT[64][64];
    const int tid = threadIdx.x;
    const int q0 = blockIdx.x * 64, t0 = blockIdx.y * 64, b = blockIdx.z;
    const int r = tid >> 4, c4 = tid & 15;
#pragma unroll
    for (int i = 0; i < 4; ++i) {
        const int qq = r + i * 16;
        int4 d4 = *(const int4*)&dist[((size_t)(b * S_ + q0 + qq)) * S_ + t0 + c4 * 4];
        sT[c4*4+0][qq] = (uint8_t)min(max(d4.x, 0), 4);
        sT[c4*4+1][qq] = (uint8_t)min(max(d4.y, 0), 4);
        sT[c4*4+2][qq] = (uint8_t)min(max(d4.z, 0), 4);
        sT[c4*4+3][qq] = (uint8_t)min(max(d4.w, 0), 4);
    }
    __syncthreads();
    const int kk = tid >> 2, qc = tid & 3;
    int4 v = *(const int4*)&sT[kk][qc * 16];
    *(int4*)&dT[((size_t)(b * S_ + t0 + kk)) * S_ + q0 + qc * 16] = v;
}

// ---------------------------------------------------------------------------
// x (f32) -> bf16, vectorized 8/thread
// ---------------------------------------------------------------------------
__global__ void convert_bf16(const float* __restrict__ src, uint16_t* __restrict__ dst, int n8)
{
    const int i = blockIdx.x * 256 + threadIdx.x;
    if (i >= n8) return;
    float4 a = *(const float4*)&src[(size_t)i * 8];
    float4 b = *(const float4*)&src[(size_t)i * 8 + 4];
    uint4 o{pack2bf(a.x, a.y), pack2bf(a.z, a.w), pack2bf(b.x, b.y), pack2bf(b.z, b.w)};
    *(uint4*)&dst[(size_t)i * 8] = o;
}

// ---------------------------------------------------------------------------
// Weight transpose+convert: W[K][512] f32 -> Wt[512][K] bf16.
// Layout (layer-major QKV for the merged GEMM):
//  off 0:                 Win^T              [512][768]
//  off F*E + (l*3+0)*E*E: Wq[l]^T            [512][512]
//  off F*E + (l*3+1)*E*E: Wk[l]^T
//  off F*E + (l*3+2)*E*E: Wv[l]^T
//  off F*E + 12*E*E + l*E*E: Wo[l]^T
// ---------------------------------------------------------------------------
__global__ __launch_bounds__(256, 2)
void wtrans(const float* __restrict__ Win, const float* __restrict__ Wq,
            const float* __restrict__ Wk, const float* __restrict__ Wv,
            const float* __restrict__ Wo, uint16_t* __restrict__ Wt)
{
    __shared__ float ls[64][65];
    const int idx = blockIdx.z;
    const int Ki = (idx == 0) ? F_ : E_;
    if (blockIdx.x * 64 >= Ki) return;
    const float* src;
    size_t dstoff;
    if (idx == 0) { src = Win; dstoff = 0; }
    else {
        const int l = (idx - 1) >> 2, which = (idx - 1) & 3;
        if (which == 0)      { src = Wq + (size_t)l*E_*E_; dstoff = (size_t)F_*E_ + (size_t)(l*3+0)*E_*E_; }
        else if (which == 1) { src = Wk + (size_t)l*E_*E_; dstoff = (size_t)F_*E_ + (size_t)(l*3+1)*E_*E_; }
        else if (which == 2) { src = Wv + (size_t)l*E_*E_; dstoff = (size_t)F_*E_ + (size_t)(l*3+2)*E_*E_; }
        else                 { src = Wo + (size_t)l*E_*E_; dstoff = (size_t)F_*E_ + (size_t)12*E_*E_ + (size_t)l*E_*E_; }
    }
    uint16_t* dst = Wt + dstoff;
    const int k0 = blockIdx.x * 64, n0 = blockIdx.y * 64;
    const int tid = threadIdx.x;
    const int r = tid >> 4, c4 = tid & 15;
#pragma unroll
    for (int i = 0; i < 4; ++i)
        *(float4*)&ls[r + i*16][c4*4] = *(const float4*)&src[(size_t)(k0 + r + i*16) * E_ + n0 + c4*4];
    __syncthreads();
#pragma unroll
    for (int i = 0; i < 2; ++i) {
        const int chunk = tid + 256 * i;        // 0..511
        const int n = chunk >> 3, kc = chunk & 7;
        uint4 o{pack2bf(ls[kc*8+0][n], ls[kc*8+1][n]),
                pack2bf(ls[kc*8+2][n], ls[kc*8+3][n]),
                pack2bf(ls[kc*8+4][n], ls[kc*8+5][n]),
                pack2bf(ls[kc*8+6][n], ls[kc*8+7][n])};
        *(uint4*)&dst[((size_t)(n0 + n)) * Ki + k0 + kc * 8] = o;
    }
}

// ---------------------------------------------------------------------------
// Residual + LayerNorm (fp32) + bf16 mirror write. One wave per row.
// ---------------------------------------------------------------------------
__global__ __launch_bounds__(256, 8)
void residual_ln(float* __restrict__ h, const float* __restrict__ o,
                 const float* __restrict__ g, const float* __restrict__ beta,
                 uint16_t* __restrict__ hb)
{
    const int wave = threadIdx.x >> 6;
    const int lane = threadIdx.x & 63;
    const int row  = blockIdx.x * 4 + wave;

    float* hr = h + (size_t)row * E_;
    const float* orow = o + (size_t)row * E_;

    float x[8];
    {
        float4 a  = *(const float4*)&hr[lane*4];
        float4 b4 = *(const float4*)&hr[256 + lane*4];
        float4 oa = *(const float4*)&orow[lane*4];
        float4 obv = *(const float4*)&orow[256 + lane*4];
        x[0] = a.x + oa.x; x[1] = a.y + oa.y; x[2] = a.z + oa.z; x[3] = a.w + oa.w;
        x[4] = b4.x + obv.x; x[5] = b4.y + obv.y; x[6] = b4.z + obv.z; x[7] = b4.w + obv.w;
    }
    float sum = 0.f, sq = 0.f;
#pragma unroll
    for (int i = 0; i < 8; ++i) { sum += x[i]; sq += x[i]*x[i]; }
#pragma unroll
    for (int off = 1; off < 64; off <<= 1) {
        sum += __shfl_xor(sum, off, 64);
        sq  += __shfl_xor(sq,  off, 64);
    }
    const float mean = sum * (1.f/512.f);
    const float var  = sq * (1.f/512.f) - mean*mean;
    const float inv  = rsqrtf(var + EPS_);

    float4 g0 = *(const float4*)&g[lane*4];
    float4 g1 = *(const float4*)&g[256 + lane*4];
    float4 be0 = *(const float4*)&beta[lane*4];
    float4 be1 = *(const float4*)&beta[256 + lane*4];

    float4 y0, y1;
    y0.x = (x[0]-mean)*inv*g0.x + be0.x;
    y0.y = (x[1]-mean)*inv*g0.y + be0.y;
    y0.z = (x[2]-mean)*inv*g0.z + be0.z;
    y0.w = (x[3]-mean)*inv*g0.w + be0.w;
    y1.x = (x[4]-mean)*inv*g1.x + be1.x;
    y1.y = (x[5]-mean)*inv*g1.y + be1.y;
    y1.z = (x[6]-mean)*inv*g1.z + be1.z;
    y1.w = (x[7]-mean)*inv*g1.w + be1.w;
    *(float4*)&hr[lane*4] = y0;
    *(float4*)&hr[256 + lane*4] = y1;

    uint16_t* hrow = hb + (size_t)row * E_;
    uint2 p0{pack2bf(y0.x, y0.y), pack2bf(y0.z, y0.w)};
    uint2 p1{pack2bf(y1.x, y1.y), pack2bf(y1.z, y1.w)};
    *(uint2*)&hrow[lane*4]       = p0;
    *(uint2*)&hrow[256 + lane*4] = p1;
}

// ---------------------------------------------------------------------------
// Final head (fp32, tiny): t = h[b,0,:]; relu(t@W1+b1)@W2+b2.
// ---------------------------------------------------------------------------
__global__ __launch_bounds__(256, 1)
void head_kernel(const float* __restrict__ h, const float* __restrict__ W1,
                 const float* __restrict__ b1, const float* __restrict__ W2,
                 const float* __restrict__ b2, float* __restrict__ out)
{
    __shared__ float tl[512];
    __shared__ float red[8];
    const int tid = threadIdx.x;
    const int b = blockIdx.x;

    const float* hr = h + (size_t)b * S_ * E_;
    *(float2*)&tl[tid*2] = *(const float2*)&hr[tid*2];
    __syncthreads();

    float acc = b1[tid];
    for (int kk = 0; kk < 512; ++kk)
        acc = fmaf(tl[kk], W1[kk * 256 + tid], acc);
    float hid = fmaxf(acc, 0.f);

    float p0 = hid * W2[tid*2 + 0];
    float p1 = hid * W2[tid*2 + 1];
#pragma unroll
    for (int off = 32; off; off >>= 1) {
        p0 += __shfl_down(p0, off, 64);
        p1 += __shfl_down(p1, off, 64);
    }
    if ((tid & 63) == 0) {
        red[(tid >> 6)*2 + 0] = p0;
        red[(tid >> 6)*2 + 1] = p1;
    }
    __syncthreads();
    if (tid == 0) {
        out[b*2 + 0] = red[0] + red[2] + red[4] + red[6] + b2[0];
        out[b*2 + 1] = red[1] + red[3] + red[5] + red[7] + b2[1];
    }
}

// ---------------------------------------------------------------------------
extern "C" void kernel_launch(void* const* d_in, const int* in_sizes, int n_in,
                              void* d_out, int out_size, void* d_ws, size_t ws_size,
                              hipStream_t stream)
{
    const float* x     = (const float*)d_in[0];
    const int*   dist  = (const int*)  d_in[1];
    const float* Win   = (const float*)d_in[2];
    const float* b_in  = (const float*)d_in[3];
    const float* Wq    = (const float*)d_in[4];
    const float* bq    = (const float*)d_in[5];
    const float* Wk    = (const float*)d_in[6];
    const float* bk    = (const float*)d_in[7];
    const float* Wv    = (const float*)d_in[8];
    const float* bv    = (const float*)d_in[9];
    const float* Wo    = (const float*)d_in[10];
    const float* bo    = (const float*)d_in[11];
    const float* dbias = (const float*)d_in[12];
    const float* ln_g  = (const float*)d_in[13];
    const float* ln_b  = (const float*)d_in[14];
    const float* W1    = (const float*)d_in[15];
    const float* b1    = (const float*)d_in[16];
    const float* W2    = (const float*)d_in[17];
    const float* b2    = (const float*)d_in[18];
    float* out = (float*)d_out;

    char* w8 = (char*)d_ws;
    float*    h    = (float*)   (w8);                      // 16 MB fp32 residual stream
    float*    pb   = (float*)   (w8 + (size_t)(16<<20));   // 16 MB fp32 o-proj out
    uint16_t* hbf  = (uint16_t*)(w8 + (size_t)(32<<20));   // 8 MB bf16 mirror of h
    uint16_t* qb   = (uint16_t*)(w8 + (size_t)(40<<20));   // 8 MB
    uint16_t* kb   = (uint16_t*)(w8 + (size_t)(48<<20));   // 8 MB
    uint16_t* vTb  = (uint16_t*)(w8 + (size_t)(56<<20));   // 8 MB  vT[b][col][s]
    uint16_t* obuf = (uint16_t*)(w8 + (size_t)(64<<20));   // 8 MB
    uint16_t* xb   = (uint16_t*)(w8 + (size_t)(72<<20));   // 12 MB
    uint16_t* Wt   = (uint16_t*)(w8 + (size_t)(84<<20));   // 8.75 MB transposed bf16 weights
    uint8_t*  dT   = (uint8_t*) (w8 + (size_t)(93<<20));   // 8 MB clipped dist^T

    const dim3 blk(256);
    const dim3 ggrid(E_/64, M_/128);       // (8, 64)
    const dim3 qkvgrid(3*E_/64, M_/128);   // (24, 64)

    convert_bf16<<<dim3(M_*F_/8/256), blk, 0, stream>>>(x, xb, M_*F_/8);
    wtrans<<<dim3(12, 8, 17), blk, 0, stream>>>(Win, Wq, Wk, Wv, Wo, Wt);
    dist_transpose<<<dim3(16, 16, 8), blk, 0, stream>>>(dist, dT);

    // h = x @ Win + b_in  (fp32 + bf16 mirror)
    gemm_mfma<2><<<ggrid, blk, 0, stream>>>(xb, Wt, b_in, h, hbf, F_);

    for (int l = 0; l < L_; ++l) {
        const uint16_t* Wqkv = Wt + (size_t)F_*E_ + (size_t)(l*3)*E_*E_;
        const uint16_t* Wto  = Wt + (size_t)F_*E_ + (size_t)12*E_*E_ + (size_t)l*E_*E_;
        gemm_qkv<<<qkvgrid, blk, 0, stream>>>(hbf, Wqkv, bq + l*E_, bk + l*E_, bv + l*E_,
                                              qb, kb, vTb);
        attn_mfma<<<dim3(B_*H_*16), blk, 0, stream>>>(qb, kb, vTb, dT, dbias, l, obuf);
        gemm_mfma<1><<<ggrid, blk, 0, stream>>>(obuf, Wto, bo + l*E_, pb, nullptr, E_);
        residual_ln<<<dim3(M_/4), blk, 0, stream>>>(h, pb, ln_g + l*E_, ln_b + l*E_, hbf);
    }

    head_kernel<<<dim3(B_), blk, 0, stream>>>(h, W1, b1, W2, b2, out);
}

// Round 8
// 609.711 us; speedup vs baseline: 4.5108x; 1.0098x over previous
//
#include <hip/hip_runtime.h>
#include <hip/hip_bf16.h>
#include <stdint.h>

// Problem constants
#define B_   8
#define S_   1024
#define F_   768
#define E_   512
#define L_   4
#define H_   8
#define HD_  64
#define M_   (B_*S_)        // 8192 rows
#define EPS_ 1e-5f
#define LOG2E_ 1.44269504089f
#define SL2E_  (0.125f * LOG2E_)   // SCALE * log2(e), folded into Q

typedef short bf8_t  __attribute__((ext_vector_type(8)));   // 8 bf16 = 4 VGPR (MFMA A/B frag)
typedef float f32x4  __attribute__((ext_vector_type(4)));   // MFMA C/D frag

static __device__ __forceinline__ uint16_t bfbits(float f) {
    __hip_bfloat16 h = __float2bfloat16(f);
    union { __hip_bfloat16 h; uint16_t u; } cv{h};
    return cv.u;
}
static __device__ __forceinline__ uint32_t pack2bf(float lo, float hi) {
    return (uint32_t)bfbits(lo) | ((uint32_t)bfbits(hi) << 16);
}
static __device__ __forceinline__ float asf(uint32_t u) {
    union { uint32_t u; float f; } cv{u};
    return cv.f;
}

// ---------------------------------------------------------------------------
// Swizzled global->LDS staging (T2 both-sides pattern, m173/m201):
// LDS layout: [ROWS][8 slots of 16B] linear; slot holds data kc8 = slot ^ (row&7).
// global_load_lds writes lane*16 linearly, so the SOURCE address is pre-swizzled.
// ---------------------------------------------------------------------------
template<int ROWS>
static __device__ __forceinline__ void stage_swz(const uint16_t* __restrict__ g, int ldK,
                                                 int k0, char* lds, int tid) {
    const int wave = tid >> 6, lane = tid & 63;
    constexpr int NI = ROWS / 8;          // 1KB wave-instrs for this tile
    constexpr int PW = NI / 4;            // per wave (4 waves)
#pragma unroll
    for (int j = 0; j < PW; ++j) {
        const int I = wave * PW + j;                  // wave-uniform
        const int m = I * 8 + (lane >> 3);
        const int slot = lane & 7;
        const int kc8 = slot ^ (m & 7);
        const uint16_t* gp = g + (size_t)m * ldK + k0 + kc8 * 8;
        __builtin_amdgcn_global_load_lds((const __attribute__((address_space(1))) void*)gp,
                                         (__attribute__((address_space(3))) void*)(lds + I * 1024),
                                         16, 0, 0);
    }
}

// ---------------------------------------------------------------------------
// MFMA GEMM: C[M,N=512] = A[M,K] (bf16) @ Wt[N][K] (bf16) + bias.
// 128x64 tile, BK=64, 256 threads. OUT_MODE: 1 = f32, 2 = f32 + bf16 mirror.
// ---------------------------------------------------------------------------
template<int OUT_MODE>
__global__ __launch_bounds__(256, 2)
void gemm_mfma(const uint16_t* __restrict__ A, const uint16_t* __restrict__ Wt,
               const float* __restrict__ bias, void* __restrict__ Cout,
               void* __restrict__ Cout2, int K)
{
    __shared__ __align__(16) char smA[128 * 128];   // 16KB
    __shared__ __align__(16) char smB[64 * 128];    // 8KB

    const int tid = threadIdx.x;
    const int lane = tid & 63;
    const int g = lane >> 4;
    const int l15 = lane & 15;
    const int wave = tid >> 6;
    const int wm = wave >> 1;
    const int wn = wave & 1;
    const int n0 = blockIdx.x * 64;
    const int m0 = blockIdx.y * 128;

    f32x4 acc[4][2];
#pragma unroll
    for (int i = 0; i < 4; ++i) {
        acc[i][0] = f32x4{0.f, 0.f, 0.f, 0.f};
        acc[i][1] = f32x4{0.f, 0.f, 0.f, 0.f};
    }

    for (int k0 = 0; k0 < K; k0 += 64) {
        stage_swz<128>(A  + (size_t)m0 * K, K, k0, smA, tid);
        stage_swz< 64>(Wt + (size_t)n0 * K, K, k0, smB, tid);
        __syncthreads();

#pragma unroll
        for (int c = 0; c < 2; ++c) {
            bf8_t bfr[2];
#pragma unroll
            for (int nb = 0; nb < 2; ++nb) {
                const int n = wn * 32 + nb * 16 + l15;
                const int slot = (c * 4 + g) ^ (n & 7);
                bfr[nb] = *(const bf8_t*)(smB + n * 128 + slot * 16);
            }
#pragma unroll
            for (int mi = 0; mi < 4; ++mi) {
                const int m = wm * 64 + mi * 16 + l15;
                const int slot = (c * 4 + g) ^ (m & 7);
                bf8_t af = *(const bf8_t*)(smA + m * 128 + slot * 16);
#pragma unroll
                for (int nb = 0; nb < 2; ++nb)
                    acc[mi][nb] = __builtin_amdgcn_mfma_f32_16x16x32_bf16(af, bfr[nb], acc[mi][nb], 0, 0, 0);
            }
        }
        __syncthreads();
    }

    const int colbase = n0 + wn * 32;
    float bia[2] = { bias[colbase + l15], bias[colbase + 16 + l15] };

#pragma unroll
    for (int mi = 0; mi < 4; ++mi) {
#pragma unroll
        for (int nb = 0; nb < 2; ++nb) {
            const int col  = colbase + nb * 16 + l15;
            const int row0 = m0 + wm * 64 + mi * 16 + g * 4;   // C/D: row=(l>>4)*4+reg (m89)
            f32x4 v = acc[mi][nb];
            const float r0 = v.x + bia[nb], r1 = v.y + bia[nb];
            const float r2 = v.z + bia[nb], r3 = v.w + bia[nb];
            if (OUT_MODE == 1) {
                float* C = (float*)Cout;
                C[(size_t)(row0+0)*E_ + col] = r0;
                C[(size_t)(row0+1)*E_ + col] = r1;
                C[(size_t)(row0+2)*E_ + col] = r2;
                C[(size_t)(row0+3)*E_ + col] = r3;
            } else {
                float* C = (float*)Cout;
                uint16_t* C2 = (uint16_t*)Cout2;
                C[(size_t)(row0+0)*E_ + col] = r0;
                C[(size_t)(row0+1)*E_ + col] = r1;
                C[(size_t)(row0+2)*E_ + col] = r2;
                C[(size_t)(row0+3)*E_ + col] = r3;
                C2[(size_t)(row0+0)*E_ + col] = bfbits(r0);
                C2[(size_t)(row0+1)*E_ + col] = bfbits(r1);
                C2[(size_t)(row0+2)*E_ + col] = bfbits(r2);
                C2[(size_t)(row0+3)*E_ + col] = bfbits(r3);
            }
        }
    }
}

// ---------------------------------------------------------------------------
// Merged QKV GEMM, 128x128 tile, BK=64, 4 waves each 64x64 (4x4 frags).
// N=1536: sections of 512 cols (q,k,v per layer-major Wt). Q output is
// pre-scaled by SL2E_ (folds attention SCALE*log2e). V written transposed.
// ---------------------------------------------------------------------------
__global__ __launch_bounds__(256, 2)
void gemm_qkv(const uint16_t* __restrict__ A, const uint16_t* __restrict__ Wt,
              const float* __restrict__ bqp, const float* __restrict__ bkp,
              const float* __restrict__ bvp,
              uint16_t* __restrict__ qb, uint16_t* __restrict__ kb,
              uint16_t* __restrict__ vTb)
{
    __shared__ __align__(16) char smA[128 * 128];   // 16KB
    __shared__ __align__(16) char smB[128 * 128];   // 16KB

    const int tid = threadIdx.x;
    const int lane = tid & 63;
    const int g = lane >> 4;
    const int l15 = lane & 15;
    const int wave = tid >> 6;
    const int wm = wave >> 1;            // m-offset 64*wm
    const int wn = wave & 1;             // n-offset 64*wn
    const int n0 = blockIdx.x * 128;     // 0..1535
    const int m0 = blockIdx.y * 128;

    f32x4 acc[4][4];
#pragma unroll
    for (int i = 0; i < 4; ++i)
#pragma unroll
        for (int j = 0; j < 4; ++j) acc[i][j] = f32x4{0.f, 0.f, 0.f, 0.f};

    for (int k0 = 0; k0 < E_; k0 += 64) {
        stage_swz<128>(A  + (size_t)m0 * E_, E_, k0, smA, tid);
        stage_swz<128>(Wt + (size_t)n0 * E_, E_, k0, smB, tid);
        __syncthreads();

#pragma unroll
        for (int c = 0; c < 2; ++c) {
            bf8_t bfr[4];
#pragma unroll
            for (int nj = 0; nj < 4; ++nj) {
                const int n = wn * 64 + nj * 16 + l15;
                const int slot = (c * 4 + g) ^ (n & 7);
                bfr[nj] = *(const bf8_t*)(smB + n * 128 + slot * 16);
            }
#pragma unroll
            for (int mi = 0; mi < 4; ++mi) {
                const int m = wm * 64 + mi * 16 + l15;
                const int slot = (c * 4 + g) ^ (m & 7);
                bf8_t af = *(const bf8_t*)(smA + m * 128 + slot * 16);
#pragma unroll
                for (int nj = 0; nj < 4; ++nj)
                    acc[mi][nj] = __builtin_amdgcn_mfma_f32_16x16x32_bf16(af, bfr[nj], acc[mi][nj], 0, 0, 0);
            }
        }
        __syncthreads();
    }

    const int sec = (n0 + wn * 64) >> 9;       // 0=q 1=k 2=v (wave-half never straddles)
    const float* bp = sec == 0 ? bqp : sec == 1 ? bkp : bvp;
    const int cbase = (n0 + wn * 64) & 511;

#pragma unroll
    for (int mi = 0; mi < 4; ++mi) {
#pragma unroll
        for (int nj = 0; nj < 4; ++nj) {
            const int col  = cbase + nj * 16 + l15;       // 0..511 within section
            const int row0 = m0 + wm * 64 + mi * 16 + g * 4;
            const float bia = bp[col];
            f32x4 v = acc[mi][nj];
            float r0 = v.x + bia, r1 = v.y + bia, r2 = v.z + bia, r3 = v.w + bia;
            if (sec == 0) { r0 *= SL2E_; r1 *= SL2E_; r2 *= SL2E_; r3 *= SL2E_; }
            if (sec < 2) {
                uint16_t* C = sec == 0 ? qb : kb;
                C[(size_t)(row0+0)*E_ + col] = bfbits(r0);
                C[(size_t)(row0+1)*E_ + col] = bfbits(r1);
                C[(size_t)(row0+2)*E_ + col] = bfbits(r2);
                C[(size_t)(row0+3)*E_ + col] = bfbits(r3);
            } else {
                const int b  = row0 >> 10;
                const int s0 = row0 & 1023;
                uint2 val{pack2bf(r0, r1), pack2bf(r2, r3)};
                *(uint2*)&vTb[((size_t)(b * E_ + col)) * S_ + s0] = val;
            }
        }
    }
}

// ---------------------------------------------------------------------------
// Per-layer bias table: biasL[b][q][key] = bf16(dbias5[clip(d,0,4)] * log2e).
// dist is already [b][q][key] -> pure elementwise, coalesced both sides.
// 16MB output; recomputed per layer to stay inside the workspace budget.
// ---------------------------------------------------------------------------
__global__ __launch_bounds__(256, 8)
void dist_bias_layer(const int* __restrict__ dist, const float* __restrict__ dbias5,
                     uint16_t* __restrict__ biasL)
{
    const size_t base = ((size_t)blockIdx.x * 256 + threadIdx.x) * 16;
    const float t0 = dbias5[0] * LOG2E_, t1 = dbias5[1] * LOG2E_,
                t2 = dbias5[2] * LOG2E_, t3 = dbias5[3] * LOG2E_,
                t4 = dbias5[4] * LOG2E_;
    uint32_t w[8];
#pragma unroll
    for (int j = 0; j < 4; ++j) {
        int4 v = *(const int4*)&dist[base + j * 4];
        const int d0 = min(max(v.x, 0), 4), d1 = min(max(v.y, 0), 4);
        const int d2 = min(max(v.z, 0), 4), d3 = min(max(v.w, 0), 4);
        const float s0 = d0==0 ? t0 : d0==1 ? t1 : d0==2 ? t2 : d0==3 ? t3 : t4;
        const float s1 = d1==0 ? t0 : d1==1 ? t1 : d1==2 ? t2 : d1==3 ? t3 : t4;
        const float s2 = d2==0 ? t0 : d2==1 ? t1 : d2==2 ? t2 : d2==3 ? t3 : t4;
        const float s3 = d3==0 ? t0 : d3==1 ? t1 : d3==2 ? t2 : d3==3 ? t3 : t4;
        w[j*2+0] = pack2bf(s0, s1);
        w[j*2+1] = pack2bf(s2, s3);
    }
    uint16_t* dst = biasL + base;
    *(uint4*)dst       = uint4{w[0], w[1], w[2], w[3]};
    *(uint4*)(dst + 8) = uint4{w[4], w[5], w[6], w[7]};
}

// ---------------------------------------------------------------------------
// MFMA flash attention v4: LDS double-buffered K/V, bias folded into the
// QK^T C-operand (prefetched uint2 loads), exp2-domain softmax, defer-max,
// XCD-chunked block swizzle. Block = 4 waves, one (b, head, 64-q tile).
// ---------------------------------------------------------------------------
__global__ __launch_bounds__(256, 4)
void attn_mfma(const uint16_t* __restrict__ q, const uint16_t* __restrict__ k,
               const uint16_t* __restrict__ vT, const uint16_t* __restrict__ biasL,
               uint16_t* __restrict__ ob)
{
    __shared__ __align__(16) char Kb[2][64 * 128];   // 8KB per buf
    __shared__ __align__(16) char Vb[2][64 * 128];   // V^T: rows=hd, cols=keys

    const int tid = threadIdx.x, lane = tid & 63;
    const int g = lane >> 4, l15 = lane & 15, wq = tid >> 6;
    // T1: XCD-chunked bijective swizzle (2048 % 8 == 0): each XCD gets 2 batches.
    const int bid0 = blockIdx.x;
    const int bid = (bid0 & 7) * 256 + (bid0 >> 3);
    const int qt = bid & 15, hh = (bid >> 4) & 7, b = bid >> 7;
    const int qrow = qt * 64 + wq * 16 + l15;

    // Q frags (pre-scaled by SL2E_ in gemm_qkv)
    bf8_t qf[2];
    const uint16_t* qbase = q + ((size_t)(b * S_ + qrow)) * E_ + hh * 64;
#pragma unroll
    for (int c = 0; c < 2; ++c) qf[c] = *(const bf8_t*)(qbase + c * 32 + g * 8);

    f32x4 accO[4];
#pragma unroll
    for (int f = 0; f < 4; ++f) accO[f] = f32x4{0.f, 0.f, 0.f, 0.f};
    float mrun = -1e30f, lrun = 0.f;

    const uint16_t* kTile = k  + ((size_t)(b * S_)) * E_ + hh * 64;   // + key*E_
    const uint16_t* vTile = vT + ((size_t)(b * E_ + hh * 64)) * S_;   // + hd*S_ + key
    const uint16_t* bbase = biasL + ((size_t)b << 20) + ((size_t)qrow << 10);

    // ---- prologue: stage tile 0, prefetch bias for tile 0 ----
    stage_swz<64>(kTile, E_, 0, Kb[0], tid);
    stage_swz<64>(vTile, S_, 0, Vb[0], tid);
    uint2 bcur[4];
#pragma unroll
    for (int f = 0; f < 4; ++f)
        bcur[f] = *(const uint2*)(bbase + f * 16 + g * 4);
    __syncthreads();

    for (int t = 0; t < 16; ++t) {
        const int cur = t & 1;
        char* kc_ = Kb[cur];
        char* vc_ = Vb[cur];
        if (t < 15) {
            stage_swz<64>(kTile + (size_t)(t + 1) * 64 * E_, E_, 0, Kb[cur ^ 1], tid);
            stage_swz<64>(vTile, S_, (t + 1) * 64, Vb[cur ^ 1], tid);
        }
        uint2 bnxt[4];
#pragma unroll
        for (int f = 0; f < 4; ++f)
            bnxt[f] = (t < 15) ? *(const uint2*)(bbase + (t + 1) * 64 + f * 16 + g * 4)
                               : uint2{0, 0};

        // ---- S^T = K . Q^T + bias (C-init) ----
        f32x4 sc[4];
#pragma unroll
        for (int f = 0; f < 4; ++f) {
            const uint2 w = bcur[f];
            sc[f] = f32x4{asf(w.x << 16), asf(w.x & 0xffff0000u),
                          asf(w.y << 16), asf(w.y & 0xffff0000u)};
        }
        __builtin_amdgcn_s_setprio(1);
#pragma unroll
        for (int f = 0; f < 4; ++f) {
#pragma unroll
            for (int c = 0; c < 2; ++c) {
                const int slot = (c * 4 + g) ^ (l15 & 7);
                bf8_t kf = *(const bf8_t*)(kc_ + (f*16 + l15) * 128 + slot * 16);
                sc[f] = __builtin_amdgcn_mfma_f32_16x16x32_bf16(kf, qf[c], sc[f], 0, 0, 0);
            }
        }
        __builtin_amdgcn_s_setprio(0);

        // ---- online softmax in exp2 domain (rows lane-local) ----
        float tmax = -1e30f;
#pragma unroll
        for (int f = 0; f < 4; ++f) {
            tmax = fmaxf(tmax, fmaxf(fmaxf(sc[f][0], sc[f][1]), fmaxf(sc[f][2], sc[f][3])));
        }
        tmax = fmaxf(tmax, __shfl_xor(tmax, 16, 64));
        tmax = fmaxf(tmax, __shfl_xor(tmax, 32, 64));
        if (__any(tmax > mrun + 11.0f)) {        // T13 defer-max: rescale rarely
            const float mnew = fmaxf(mrun, tmax);
            const float corr = exp2f(mrun - mnew);
            lrun *= corr;
#pragma unroll
            for (int f = 0; f < 4; ++f) accO[f] *= corr;
            mrun = mnew;
        }
        float p[4][4];
        float psum = 0.f;
#pragma unroll
        for (int f = 0; f < 4; ++f)
#pragma unroll
            for (int r = 0; r < 4; ++r) {
                p[f][r] = exp2f(sc[f][r] - mrun);
                psum += p[f][r];
            }
        psum += __shfl_xor(psum, 16, 64);
        psum += __shfl_xor(psum, 32, 64);
        lrun += psum;

        // ---- pack P; redistribute S^T-layout -> B-frag layout ----
        uint32_t pk[4][2];
#pragma unroll
        for (int f = 0; f < 4; ++f) {
            pk[f][0] = pack2bf(p[f][0], p[f][1]);
            pk[f][1] = pack2bf(p[f][2], p[f][3]);
        }
        bf8_t pB[2];
#pragma unroll
        for (int c = 0; c < 2; ++c) {
            union { uint32_t w[4]; bf8_t v; } u;
#pragma unroll
            for (int j = 0; j < 4; ++j) {
                const int src = (((2*g + (j >> 1)) & 3) * 16) + l15;
                const uint32_t a  = (uint32_t)__shfl((int)pk[c*2+0][j & 1], src, 64);
                const uint32_t bb = (uint32_t)__shfl((int)pk[c*2+1][j & 1], src, 64);
                u.w[j] = (g >= 2) ? bb : a;
            }
            pB[c] = u.v;
        }

        // ---- O^T += V^T . P^T ----
        __builtin_amdgcn_s_setprio(1);
#pragma unroll
        for (int c = 0; c < 2; ++c) {
#pragma unroll
            for (int f = 0; f < 4; ++f) {
                const int slot = (c * 4 + g) ^ (l15 & 7);
                bf8_t vf = *(const bf8_t*)(vc_ + (f*16 + l15) * 128 + slot * 16);
                accO[f] = __builtin_amdgcn_mfma_f32_16x16x32_bf16(vf, pB[c], accO[f], 0, 0, 0);
            }
        }
        __builtin_amdgcn_s_setprio(0);

        __syncthreads();   // staging of t+1 drained; all waves done with buf[cur]
#pragma unroll
        for (int f = 0; f < 4; ++f) bcur[f] = bnxt[f];
    }

    // epilogue: normalize, write ob[b*S+q][hh*64+hd] bf16 (hd = f*16+g*4+r)
    const float inv = 1.f / lrun;
    uint16_t* obase = ob + ((size_t)(b * S_ + qrow)) * E_ + hh * 64;
#pragma unroll
    for (int f = 0; f < 4; ++f) {
        f32x4 v = accO[f];
        uint2 val{pack2bf(v.x * inv, v.y * inv), pack2bf(v.z * inv, v.w * inv)};
        *(uint2*)(obase + f * 16 + g * 4) = val;
    }
}

// ---------------------------------------------------------------------------
// x (f32) -> bf16, vectorized 8/thread
// ---------------------------------------------------------------------------
__global__ void convert_bf16(const float* __restrict__ src, uint16_t* __restrict__ dst, int n8)
{
    const int i = blockIdx.x * 256 + threadIdx.x;
    if (i >= n8) return;
    float4 a = *(const float4*)&src[(size_t)i * 8];
    float4 b = *(const float4*)&src[(size_t)i * 8 + 4];
    uint4 o{pack2bf(a.x, a.y), pack2bf(a.z, a.w), pack2bf(b.x, b.y), pack2bf(b.z, b.w)};
    *(uint4*)&dst[(size_t)i * 8] = o;
}

// ---------------------------------------------------------------------------
// Weight transpose+convert: W[K][512] f32 -> Wt[512][K] bf16.
// Layout: Win^T @0; Wq/Wk/Wv layer-major at F*E + (l*3+{0,1,2})*E*E;
//         Wo^T at F*E + 12*E*E + l*E*E.
// ---------------------------------------------------------------------------
__global__ __launch_bounds__(256, 2)
void wtrans(const float* __restrict__ Win, const float* __restrict__ Wq,
            const float* __restrict__ Wk, const float* __restrict__ Wv,
            const float* __restrict__ Wo, uint16_t* __restrict__ Wt)
{
    __shared__ float ls[64][65];
    const int idx = blockIdx.z;
    const int Ki = (idx == 0) ? F_ : E_;
    if (blockIdx.x * 64 >= Ki) return;
    const float* src;
    size_t dstoff;
    if (idx == 0) { src = Win; dstoff = 0; }
    else {
        const int l = (idx - 1) >> 2, which = (idx - 1) & 3;
        if (which == 0)      { src = Wq + (size_t)l*E_*E_; dstoff = (size_t)F_*E_ + (size_t)(l*3+0)*E_*E_; }
        else if (which == 1) { src = Wk + (size_t)l*E_*E_; dstoff = (size_t)F_*E_ + (size_t)(l*3+1)*E_*E_; }
        else if (which == 2) { src = Wv + (size_t)l*E_*E_; dstoff = (size_t)F_*E_ + (size_t)(l*3+2)*E_*E_; }
        else                 { src = Wo + (size_t)l*E_*E_; dstoff = (size_t)F_*E_ + (size_t)12*E_*E_ + (size_t)l*E_*E_; }
    }
    uint16_t* dst = Wt + dstoff;
    const int k0 = blockIdx.x * 64, n0 = blockIdx.y * 64;
    const int tid = threadIdx.x;
    const int r = tid >> 4, c4 = tid & 15;
#pragma unroll
    for (int i = 0; i < 4; ++i)
        *(float4*)&ls[r + i*16][c4*4] = *(const float4*)&src[(size_t)(k0 + r + i*16) * E_ + n0 + c4*4];
    __syncthreads();
#pragma unroll
    for (int i = 0; i < 2; ++i) {
        const int chunk = tid + 256 * i;        // 0..511
        const int n = chunk >> 3, kc = chunk & 7;
        uint4 o{pack2bf(ls[kc*8+0][n], ls[kc*8+1][n]),
                pack2bf(ls[kc*8+2][n], ls[kc*8+3][n]),
                pack2bf(ls[kc*8+4][n], ls[kc*8+5][n]),
                pack2bf(ls[kc*8+6][n], ls[kc*8+7][n])};
        *(uint4*)&dst[((size_t)(n0 + n)) * Ki + k0 + kc * 8] = o;
    }
}

// ---------------------------------------------------------------------------
// Residual + LayerNorm (fp32) + bf16 mirror write. One wave per row.
// ---------------------------------------------------------------------------
__global__ __launch_bounds__(256, 8)
void residual_ln(float* __restrict__ h, const float* __restrict__ o,
                 const float* __restrict__ g, const float* __restrict__ beta,
                 uint16_t* __restrict__ hb)
{
    const int wave = threadIdx.x >> 6;
    const int lane = threadIdx.x & 63;
    const int row  = blockIdx.x * 4 + wave;

    float* hr = h + (size_t)row * E_;
    const float* orow = o + (size_t)row * E_;

    float x[8];
    {
        float4 a  = *(const float4*)&hr[lane*4];
        float4 b4 = *(const float4*)&hr[256 + lane*4];
        float4 oa = *(const float4*)&orow[lane*4];
        float4 obv = *(const float4*)&orow[256 + lane*4];
        x[0] = a.x + oa.x; x[1] = a.y + oa.y; x[2] = a.z + oa.z; x[3] = a.w + oa.w;
        x[4] = b4.x + obv.x; x[5] = b4.y + obv.y; x[6] = b4.z + obv.z; x[7] = b4.w + obv.w;
    }
    float sum = 0.f, sq = 0.f;
#pragma unroll
    for (int i = 0; i < 8; ++i) { sum += x[i]; sq += x[i]*x[i]; }
#pragma unroll
    for (int off = 1; off < 64; off <<= 1) {
        sum += __shfl_xor(sum, off, 64);
        sq  += __shfl_xor(sq,  off, 64);
    }
    const float mean = sum * (1.f/512.f);
    const float var  = sq * (1.f/512.f) - mean*mean;
    const float inv  = rsqrtf(var + EPS_);

    float4 g0 = *(const float4*)&g[lane*4];
    float4 g1 = *(const float4*)&g[256 + lane*4];
    float4 be0 = *(const float4*)&beta[lane*4];
    float4 be1 = *(const float4*)&beta[256 + lane*4];

    float4 y0, y1;
    y0.x = (x[0]-mean)*inv*g0.x + be0.x;
    y0.y = (x[1]-mean)*inv*g0.y + be0.y;
    y0.z = (x[2]-mean)*inv*g0.z + be0.z;
    y0.w = (x[3]-mean)*inv*g0.w + be0.w;
    y1.x = (x[4]-mean)*inv*g1.x + be1.x;
    y1.y = (x[5]-mean)*inv*g1.y + be1.y;
    y1.z = (x[6]-mean)*inv*g1.z + be1.z;
    y1.w = (x[7]-mean)*inv*g1.w + be1.w;
    *(float4*)&hr[lane*4] = y0;
    *(float4*)&hr[256 + lane*4] = y1;

    uint16_t* hrow = hb + (size_t)row * E_;
    uint2 p0{pack2bf(y0.x, y0.y), pack2bf(y0.z, y0.w)};
    uint2 p1{pack2bf(y1.x, y1.y), pack2bf(y1.z, y1.w)};
    *(uint2*)&hrow[lane*4]       = p0;
    *(uint2*)&hrow[256 + lane*4] = p1;
}

// ---------------------------------------------------------------------------
// Final head (fp32, tiny): t = h[b,0,:]; relu(t@W1+b1)@W2+b2.
// ---------------------------------------------------------------------------
__global__ __launch_bounds__(256, 1)
void head_kernel(const float* __restrict__ h, const float* __restrict__ W1,
                 const float* __restrict__ b1, const float* __restrict__ W2,
                 const float* __restrict__ b2, float* __restrict__ out)
{
    __shared__ float tl[512];
    __shared__ float red[8];
    const int tid = threadIdx.x;
    const int b = blockIdx.x;

    const float* hr = h + (size_t)b * S_ * E_;
    *(float2*)&tl[tid*2] = *(const float2*)&hr[tid*2];
    __syncthreads();

    float acc = b1[tid];
    for (int kk = 0; kk < 512; ++kk)
        acc = fmaf(tl[kk], W1[kk * 256 + tid], acc);
    float hid = fmaxf(acc, 0.f);

    float p0 = hid * W2[tid*2 + 0];
    float p1 = hid * W2[tid*2 + 1];
#pragma unroll
    for (int off = 32; off; off >>= 1) {
        p0 += __shfl_down(p0, off, 64);
        p1 += __shfl_down(p1, off, 64);
    }
    if ((tid & 63) == 0) {
        red[(tid >> 6)*2 + 0] = p0;
        red[(tid >> 6)*2 + 1] = p1;
    }
    __syncthreads();
    if (tid == 0) {
        out[b*2 + 0] = red[0] + red[2] + red[4] + red[6] + b2[0];
        out[b*2 + 1] = red[1] + red[3] + red[5] + red[7] + b2[1];
    }
}

// ---------------------------------------------------------------------------
extern "C" void kernel_launch(void* const* d_in, const int* in_sizes, int n_in,
                              void* d_out, int out_size, void* d_ws, size_t ws_size,
                              hipStream_t stream)
{
    const float* x     = (const float*)d_in[0];
    const int*   dist  = (const int*)  d_in[1];
    const float* Win   = (const float*)d_in[2];
    const float* b_in  = (const float*)d_in[3];
    const float* Wq    = (const float*)d_in[4];
    const float* bq    = (const float*)d_in[5];
    const float* Wk    = (const float*)d_in[6];
    const float* bk    = (const float*)d_in[7];
    const float* Wv    = (const float*)d_in[8];
    const float* bv    = (const float*)d_in[9];
    const float* Wo    = (const float*)d_in[10];
    const float* bo    = (const float*)d_in[11];
    const float* dbias = (const float*)d_in[12];
    const float* ln_g  = (const float*)d_in[13];
    const float* ln_b  = (const float*)d_in[14];
    const float* W1    = (const float*)d_in[15];
    const float* b1    = (const float*)d_in[16];
    const float* W2    = (const float*)d_in[17];
    const float* b2    = (const float*)d_in[18];
    float* out = (float*)d_out;

    // Workspace layout — peak 98MB (round-3's 101MB proved safe; round-4's
    // 141MB FAILED => likely ws overflow, so bias is now per-layer 16MB):
    //  @  0MB  h     f32 16MB residual stream
    //  @ 16MB  pb    f32 16MB o-proj out  / xb bf16 12MB overlay (dead after in-proj)
    //  @ 32MB  hbf   bf16  8MB mirror of h
    //  @ 40MB  qb    bf16  8MB
    //  @ 48MB  kb    bf16  8MB
    //  @ 56MB  vTb   bf16  8MB vT[b][col][s]
    //  @ 64MB  obuf  bf16  8MB attention out
    //  @ 72MB  Wt    bf16 10MB transposed weights (needs 8.75MB)
    //  @ 82MB  biasL bf16 16MB current-layer bias[b][q][key]
    char* w8 = (char*)d_ws;
    float*    h     = (float*)   (w8);
    float*    pb    = (float*)   (w8 + (size_t)(16<<20));
    uint16_t* xb    = (uint16_t*)(w8 + (size_t)(16<<20));
    uint16_t* hbf   = (uint16_t*)(w8 + (size_t)(32<<20));
    uint16_t* qb    = (uint16_t*)(w8 + (size_t)(40<<20));
    uint16_t* kb    = (uint16_t*)(w8 + (size_t)(48<<20));
    uint16_t* vTb   = (uint16_t*)(w8 + (size_t)(56<<20));
    uint16_t* obuf  = (uint16_t*)(w8 + (size_t)(64<<20));
    uint16_t* Wt    = (uint16_t*)(w8 + (size_t)(72<<20));
    uint16_t* biasL = (uint16_t*)(w8 + (size_t)(82<<20));

    const dim3 blk(256);
    const dim3 ggrid(E_/64, M_/128);        // (8, 64) for 128x64-tile GEMMs
    const dim3 qkvgrid(3*E_/128, M_/128);   // (12, 64) = 768 blocks

    convert_bf16<<<dim3(M_*F_/8/256), blk, 0, stream>>>(x, xb, M_*F_/8);
    wtrans<<<dim3(12, 8, 17), blk, 0, stream>>>(Win, Wq, Wk, Wv, Wo, Wt);

    // h = x @ Win + b_in  (fp32 + bf16 mirror)
    gemm_mfma<2><<<ggrid, blk, 0, stream>>>(xb, Wt, b_in, h, hbf, F_);

    for (int l = 0; l < L_; ++l) {
        const uint16_t* Wqkv = Wt + (size_t)F_*E_ + (size_t)(l*3)*E_*E_;
        const uint16_t* Wto  = Wt + (size_t)F_*E_ + (size_t)12*E_*E_ + (size_t)l*E_*E_;
        dist_bias_layer<<<dim3((B_*S_*S_/16)/256), blk, 0, stream>>>(dist, dbias + l*5, biasL);
        gemm_qkv<<<qkvgrid, blk, 0, stream>>>(hbf, Wqkv, bq + l*E_, bk + l*E_, bv + l*E_,
                                              qb, kb, vTb);
        attn_mfma<<<dim3(B_*H_*16), blk, 0, stream>>>(qb, kb, vTb, biasL, obuf);
        gemm_mfma<1><<<ggrid, blk, 0, stream>>>(obuf, Wto, bo + l*E_, pb, nullptr, E_);
        residual_ln<<<dim3(M_/4), blk, 0, stream>>>(h, pb, ln_g + l*E_, ln_b + l*E_, hbf);
    }

    head_kernel<<<dim3(B_), blk, 0, stream>>>(h, W1, b1, W2, b2, out);
}